// Round 9
// baseline (221.055 us; speedup 1.0000x reference)
//
#include <hip/hip_runtime.h>
#include <hip/hip_bf16.h>
#include <math.h>

#define TB 16
#define LOG2E 1.44269504f

typedef float f32x4 __attribute__((ext_vector_type(4)));
typedef _Float16 f16x8 __attribute__((ext_vector_type(8)));
typedef _Float16 f16x4 __attribute__((ext_vector_type(4)));
typedef _Float16 f16x2 __attribute__((ext_vector_type(2)));
typedef unsigned int u32x4 __attribute__((ext_vector_type(4)));

// ---------------- ws layout (bytes), all weight mats f16 [col][k] -----------
#define OFF_W1T  344064
#define OFF_WOA  352256   // [64][64] = aWo^T
#define OFF_WOE  360448   // [64][64] = eWo^T
#define OFF_VBA  368640   // [64h][32k] = We@Wv fused (k=24 bias row)
#define OFF_VBE  372736
#define OFF_GA   376832   // [128][64]
#define OFF_GE   393216
#define OFF_GIH  409600
#define OFF_GHH  483328
#define OFF_GBS  507904
#define OFF_GBH  508672
#define OFF_BHD  508928

#define MFH(a, b, c) __builtin_amdgcn_mfma_f32_16x16x32_f16((a), (b), (c), 0, 0, 0)

__device__ inline f16x2 u2h(unsigned u) {
  union { unsigned x; f16x2 h; } c; c.x = u; return c.h;
}
__device__ inline float dot2(f16x2 a, f16x2 b, float c) {
#if __has_builtin(__builtin_amdgcn_fdot2)
  return __builtin_amdgcn_fdot2(a, b, c, false);
#else
  return c + (float)a[0] * (float)b[0] + (float)a[1] * (float)b[1];
#endif
}

// ============================================================= prep =========
__global__ __launch_bounds__(256)
void prep_kernel(const float* __restrict__ hyp_W1, const float* __restrict__ hyp_b1,
                 const float* __restrict__ hyp_W2, const float* __restrict__ hyp_b2,
                 const float* __restrict__ Wa, const float* __restrict__ ba,
                 const float* __restrict__ We, const float* __restrict__ be,
                 const float* __restrict__ aWq, const float* __restrict__ aWk,
                 const float* __restrict__ aWv, const float* __restrict__ aWo,
                 const float* __restrict__ eWq, const float* __restrict__ eWk,
                 const float* __restrict__ eWv, const float* __restrict__ eWo,
                 const float* __restrict__ gWih, const float* __restrict__ gWhh,
                 const float* __restrict__ gbih, const float* __restrict__ gbhh,
                 const float* __restrict__ WzK, const float* __restrict__ WEK,
                 const float* __restrict__ Wm,
                 void* __restrict__ ws)
{
  const int b = blockIdx.x, t = threadIdx.x;
  if (b < 42) {
    _Float16* o = (_Float16*)ws;
    for (int i = t; i < 4096; i += 256) {
      int h = i >> 6, k = i & 63;
      float v;
      if (b < 40)       v = hyp_W2[(size_t)k * 2628 + b * 64 + h];
      else if (b == 40) v = hyp_W2[(size_t)k * 2628 + 2560 + h];
      else              v = (k < 40) ? hyp_b2[k * 64 + h]
                             : (k == 40 ? hyp_b2[2560 + h] : 0.0f);
      o[b * 4096 + i] = (_Float16)v;
    }
  } else if (b == 42) {
    _Float16* o = (_Float16*)((char*)ws + OFF_W1T);
    for (int i = t; i < 4096; i += 256) {
      int h = i >> 6, k = i & 63;
      float v = (k < 40) ? hyp_W1[k * 64 + h] : (k == 40 ? hyp_b1[h] : 0.0f);
      o[i] = (_Float16)v;
    }
  } else if (b == 43 || b == 44) {
    const float* M = (b == 43) ? aWo : eWo;
    _Float16* o = (_Float16*)((char*)ws + (b == 43 ? OFF_WOA : OFF_WOE));
    for (int i = t; i < 4096; i += 256)
      o[i] = (_Float16)M[(i & 63) * 64 + (i >> 6)];
  } else if (b == 45 || b == 46) {
    const float* Wemb = (b == 45) ? Wa : We;
    const float* bemb = (b == 45) ? ba : be;
    const float* Wv   = (b == 45) ? aWv : eWv;
    _Float16* o = (_Float16*)((char*)ws + (b == 45 ? OFF_VBA : OFF_VBE));
    for (int i = t; i < 2048; i += 256) {
      int h = i >> 5, k = i & 31;
      float v = 0.f;
      if (k < 24)       { for (int d = 0; d < 64; ++d) v += Wemb[k * 64 + d] * Wv[d * 64 + h]; }
      else if (k == 24) { for (int d = 0; d < 64; ++d) v += bemb[d] * Wv[d * 64 + h]; }
      o[i] = (_Float16)v;
    }
  } else if (b == 47 || b == 48) {
    const float* Wemb = (b == 47) ? Wa : We;
    const float* bemb = (b == 47) ? ba : be;
    const float* Wk   = (b == 47) ? aWk : eWk;
    const float* Wq   = (b == 47) ? aWq : eWq;
    _Float16* o = (_Float16*)((char*)ws + (b == 47 ? OFF_GA : OFF_GE));
    __shared__ float sKb[25 * 64];
    for (int i = t; i < 1600; i += 256) {
      int k = i >> 6, c = i & 63;
      float v = 0.f;
      if (k < 24)  { for (int d = 0; d < 64; ++d) v += Wemb[k * 64 + d] * Wk[d * 64 + c]; }
      else         { for (int d = 0; d < 64; ++d) v += bemb[d] * Wk[d * 64 + c]; }
      sKb[i] = v;
    }
    __syncthreads();
    for (int i = t; i < 8192; i += 256) {
      int col = i >> 6, d = i & 63;
      int h = col >> 5, kk = col & 31;
      float v = 0.f;
      if (kk < 25)
        for (int dh = 0; dh < 16; ++dh)
          v += Wq[d * 64 + h * 16 + dh] * sKb[kk * 64 + h * 16 + dh];
      o[i] = (_Float16)(v * 0.25f * LOG2E);
    }
  } else if (b == 49) {
    _Float16* o = (_Float16*)((char*)ws + OFF_GIH);
    for (int i = t; i < 36864; i += 256) {
      int d = i / 192, c = i - d * 192;
      o[c * 192 + d] = (_Float16)gWih[i];
    }
  } else if (b == 50) {
    _Float16* o = (_Float16*)((char*)ws + OFF_GHH);
    for (int i = t; i < 12288; i += 256) {
      int d = i / 192, c = i - d * 192;
      o[c * 64 + d] = (_Float16)gWhh[i];
    }
  } else if (b == 51) {
    float* gbS = (float*)((char*)ws + OFF_GBS);
    float* gbH = (float*)((char*)ws + OFF_GBH);
    if (t < 192) gbS[t] = gbih[t] + (t < 128 ? gbhh[t] : 0.0f);
    if (t < 64)  gbH[t] = gbhh[128 + t];
  } else if (b == 52) { // head B-matrix
    __shared__ float sWsK[24 * 64];
    __shared__ float sbw[64];
    _Float16* o = (_Float16*)((char*)ws + OFF_BHD);
    for (int i = t; i < 1536; i += 256) {
      int j = i >> 6, h = i & 63;
      float v = 0.f;
      for (int c = 0; c < 64; ++c) v += We[j * 64 + c] * WEK[c * 64 + h];
      sWsK[i] = v;
    }
    if (t < 64) {
      float v = 0.f;
      for (int c = 0; c < 64; ++c) v += be[c] * WEK[c * 64 + t];
      sbw[t] = v;
    }
    __syncthreads();
    for (int i = t; i < 2048; i += 256) {
      int col = i >> 6, c = i & 63;
      float v = 0.f;
      if (col < 24)       { for (int d = 0; d < 64; ++d) v += WzK[c * 64 + d] * sWsK[col * 64 + d]; }
      else if (col == 24) { for (int d = 0; d < 64; ++d) v += WzK[c * 64 + d] * sbw[d]; }
      else if (col < 31)  v = Wm[c * 6 + (col - 25)];
      o[i] = (_Float16)v;
    }
  }
}

// ============================================================= main =========
__global__ __launch_bounds__(256, 8)
void agent_kernel(
    const float* __restrict__ own_raw, const float* __restrict__ ally_raw,
    const float* __restrict__ enemy_raw, const float* __restrict__ hidden,
    const float* __restrict__ bm,
    const void* __restrict__ ws,
    float* __restrict__ out, int BN)
{
  // LDS = 6272 (u16) + 8704 (raw chunk) + 5472 (R2 union) = 20448 B -> 8 blocks/CU
  __shared__ __align__(16) char s_all[20448];
  _Float16* s_u16 = (_Float16*)s_all;            // [16][196]
  char*     sRAW  = s_all + 6272;                // [8][16][34] f16, 16B-chunk XOR by (n&3)
  char*     sR2   = s_all + 14976;
  // ph0-2
  _Float16* s_own16 = (_Float16*)sR2;            // [16][52]
  _Float16* s_ownT  = (_Float16*)(sR2 + 1664);   // [40][16]
  _Float16* s_h116  = (_Float16*)(sR2 + 2944);   // [16][68]
  // ph3
  _Float16* s_w16 = (_Float16*)sR2;              // [16][130]
  _Float16* s_p16 = (_Float16*)(sR2 + 4160);     // [8][66]
  _Float16* s_ml  = (_Float16*)(sR2 + 5216);     // m[16][4] @0, l[16][4] @64
  _Float16* s_att16 = (_Float16*)sR2;            // [16][68] (post-PV, w16 dead)
  // ph4+
  _Float16* s_z16 = (_Float16*)sR2;              // [16][68]
  _Float16* s_t16 = (_Float16*)(sR2 + 2176);     // [16][26]
  float*    s_q   = (float*)(sR2 + 3008);        // [16][22]

  const int tid = threadIdx.x;
  const int bs0 = blockIdx.x * TB;
  const int s   = tid >> 4;
  const int ln  = tid & 15;
  const int l   = tid & 63;
  const int wv  = tid >> 6;
  const int lr  = l & 15;
  const int oct = l >> 4;

  const f16x8 ZERO8F = {0,0,0,0,0,0,0,0};
  f16x8 ONE8F = ZERO8F; ONE8F[0] = (_Float16)1.0f;
  const f32x4 ZERO4 = {0.f, 0.f, 0.f, 0.f};
  const float MASKED = -30000.0f;   // exactly f16-representable
  const float PHANT  = -31008.0f;   // < MASKED, f16-safe magnitude

  auto stage = [&](const float* rawg, int rstr, int base, int cnt) {
    for (int i = tid; i < cnt * 192; i += 256) {
      int nn = i / 192, r = i - nn * 192, s2 = r / 12, cc = r - s2 * 12;
      float2 v = *(const float2*)(rawg + (size_t)(bs0 + s2) * rstr + (base + nn) * 24 + cc * 2);
      f16x2 pk; pk[0] = (_Float16)v.x; pk[1] = (_Float16)v.y;
      int byte = cc * 4;
      int sw = ((((byte >> 4) ^ (nn & 3)) << 4) | (byte & 15));
      *(f16x2*)(sRAW + nn * 1088 + s2 * 68 + sw) = pk;
    }
  };

  // ---------------- phase 0: stage own (f16 + f16-T) + ALLY chunk0 ---------
  for (int i = tid; i < 320; i += 256) {
    int ss = i / 20, c = i - ss * 20;
    float2 v = *(const float2*)(own_raw + (size_t)(bs0 + ss) * 40 + c * 2);
    f16x2 pk; pk[0] = (_Float16)v.x; pk[1] = (_Float16)v.y;
    *(f16x2*)(s_own16 + ss * 52 + c * 2) = pk;
  }
  for (int i = tid; i < 640; i += 256) {       // ownT[f][s] f16
    int f = i >> 4, s2 = i & 15;
    s_ownT[i] = (_Float16)own_raw[(size_t)(bs0 + s2) * 40 + f];
  }
  stage(ally_raw, 360, 0, 8);
  __syncthreads();

  // ---------------- phase 1: h1 = relu(own @ W1 + b1) ----------------
  {
    const _Float16* w1t = (const _Float16*)((const char*)ws + OFF_W1T);
    f16x8 a0 = *(const f16x8*)(s_own16 + lr * 52 + oct * 8);
    f16x8 a1;
    if (oct == 0)      a1 = *(const f16x8*)(s_own16 + lr * 52 + 32);
    else if (oct == 1) a1 = ONE8F;
    else               a1 = ZERO8F;
    f16x8 b0 = *(const f16x8*)(w1t + (wv * 16 + lr) * 64 + oct * 8);
    f16x8 b1 = *(const f16x8*)(w1t + (wv * 16 + lr) * 64 + 32 + oct * 8);
    f32x4 acc = ZERO4;
    acc = MFH(a0, b0, acc);
    acc = MFH(a1, b1, acc);
    #pragma unroll
    for (int j = 0; j < 4; ++j)
      s_h116[(oct * 4 + j) * 68 + wv * 16 + lr] = (_Float16)fmaxf(acc[j], 0.f);
  }
  __syncthreads();

  // ---------------- phase 2: own_e, scale-in-accumulator -------------------
  {
    const _Float16* bb = (const _Float16*)ws + (size_t)(wv * 16 + lr) * 64 + oct * 8;
    f16x8 h0f = *(const f16x8*)(s_h116 + lr * 68 + oct * 8);
    f16x8 h1f = *(const f16x8*)(s_h116 + lr * 68 + 32 + oct * 8);
    f32x4 acc = ZERO4;
    #pragma unroll 4
    for (int f = 0; f < 40; ++f) {
      f16x8 b0 = *(const f16x8*)(bb + (size_t)f * 4096);
      f16x8 b1 = *(const f16x8*)(bb + (size_t)f * 4096 + 32);
      f32x4 y = MFH(h0f, b0, ZERO4);
      y = MFH(h1f, b1, y);
      f16x4 ovh = *(const f16x4*)(s_ownT + f * 16 + oct * 4);
      #pragma unroll
      for (int j = 0; j < 4; ++j) acc[j] += (float)ovh[j] * y[j];
    }
    f32x4 accD = ZERO4;
    {
      f16x8 b0 = *(const f16x8*)(bb + (size_t)40 * 4096);
      f16x8 b1 = *(const f16x8*)(bb + (size_t)40 * 4096 + 32);
      accD = MFH(h0f, b0, accD);
      accD = MFH(h1f, b1, accD);
    }
    {
      f16x8 b0 = *(const f16x8*)(bb + (size_t)41 * 4096);
      f16x8 b1 = *(const f16x8*)(bb + (size_t)41 * 4096 + 32);
      f16x8 a0 = *(const f16x8*)(s_own16 + lr * 52 + oct * 8);
      f16x8 a1;
      if (oct == 0)      a1 = *(const f16x8*)(s_own16 + lr * 52 + 32);
      else if (oct == 1) a1 = ONE8F;
      else               a1 = ZERO8F;
      accD = MFH(a0, b0, accD);
      accD = MFH(a1, b1, accD);
    }
    #pragma unroll
    for (int j = 0; j < 4; ++j)
      s_u16[(oct * 4 + j) * 196 + wv * 16 + lr] = (_Float16)(acc[j] + accD[j]);
  }
  __syncthreads();

  // ---------------- phase 3: MHA, chunked online-softmax -------------------
  for (int side = 0; side < 2; ++side) {
    const int n_ent = side ? 16 : 15;
    const int rstr  = side ? 384 : 360;
    const float* rawg = side ? enemy_raw : ally_raw;
    const _Float16* woT = (const _Float16*)((const char*)ws + (side ? OFF_WOE : OFF_WOA));
    const _Float16* vbT = (const _Float16*)((const char*)ws + (side ? OFF_VBE : OFF_VBA));
    const _Float16* gT  = (const _Float16*)((const char*)ws + (side ? OFF_GE  : OFF_GA));

    // --- w = own_e @ G -> w16 ---
    {
      f16x8 a0 = *(const f16x8*)(s_u16 + lr * 196 + oct * 8);
      f16x8 a1 = *(const f16x8*)(s_u16 + lr * 196 + 32 + oct * 8);
      #pragma unroll
      for (int t2 = 0; t2 < 2; ++t2) {
        int col = wv * 32 + t2 * 16 + lr;
        f16x8 b0 = *(const f16x8*)(gT + col * 64 + oct * 8);
        f16x8 b1 = *(const f16x8*)(gT + col * 64 + 32 + oct * 8);
        f32x4 acc = ZERO4;
        acc = MFH(a0, b0, acc);
        acc = MFH(a1, b1, acc);
        #pragma unroll
        for (int j = 0; j < 4; ++j)
          s_w16[(oct * 4 + j) * 130 + col] = (_Float16)acc[j];
      }
    }
    __syncthreads();

    float msx[4] = {-INFINITY, -INFINITY, -INFINITY, -INFINITY};
    float lsx[4] = {0.f, 0.f, 0.f, 0.f};
    f32x4 oaccA = ZERO4, oaccB = ZERO4;
    float mprev[4] = {-INFINITY, -INFINITY, -INFINITY, -INFINITY};
    f16x8 vbF = *(const f16x8*)(vbT + (wv * 16 + lr) * 32 + oct * 8);

    for (int c = 0; c < 2; ++c) {
      const int base = c << 3;
      const int cnt  = (n_ent - base < 8) ? (n_ent - base) : 8;
      if (c > 0) {
        stage(rawg, rstr, base, cnt);
        __syncthreads();
      }

      // --- SCORE chunk ---
      {
        float sc[4] = {PHANT, PHANT, PHANT, PHANT};
        if (ln < cnt) {
          const char* rb = sRAW + ln * 1088 + s * 68;
          const int x = (ln & 3) << 4;
          u32x4 c0 = *(const u32x4*)(rb + (0  ^ x));
          u32x4 c1 = *(const u32x4*)(rb + (16 ^ x));
          u32x4 c2 = *(const u32x4*)(rb + (32 ^ x));
          u32x4 orv = c0 | c1 | c2;
          bool msk = (orv[0] | orv[1] | orv[2] | orv[3]) != 0u;
          const _Float16* wp = s_w16 + s * 130;
          #pragma unroll
          for (int h = 0; h < 4; ++h) {
            float a = (float)wp[h * 32 + 24];
            #pragma unroll
            for (int p = 0; p < 4; ++p) {
              a = dot2(u2h(c0[p]), *(const f16x2*)(wp + h * 32 + 2 * p), a);
              a = dot2(u2h(c1[p]), *(const f16x2*)(wp + h * 32 + 8 + 2 * p), a);
              a = dot2(u2h(c2[p]), *(const f16x2*)(wp + h * 32 + 16 + 2 * p), a);
            }
            sc[h] = msk ? a : MASKED;
          }
        }
        float mx[4];
        #pragma unroll
        for (int h = 0; h < 4; ++h) mx[h] = sc[h];
        #pragma unroll
        for (int d = 1; d < 8; d <<= 1) {
          #pragma unroll
          for (int h = 0; h < 4; ++h) mx[h] = fmaxf(mx[h], __shfl_xor(mx[h], d));
        }
        float pv[4], ps[4], mn[4];
        #pragma unroll
        for (int h = 0; h < 4; ++h) {
          mn[h] = (float)(_Float16)fmaxf(msx[h], mx[h]);   // quantized running max
          pv[h] = __builtin_exp2f(sc[h] - mn[h]);
          ps[h] = pv[h];
        }
        #pragma unroll
        for (int d = 1; d < 8; d <<= 1) {
          #pragma unroll
          for (int h = 0; h < 4; ++h) ps[h] += __shfl_xor(ps[h], d);
        }
        #pragma unroll
        for (int h = 0; h < 4; ++h) {
          lsx[h] = lsx[h] * __builtin_exp2f(msx[h] - mn[h]) + ps[h];
          msx[h] = mn[h];
        }
        if (ln < 8) {
          f16x4 pk;
          #pragma unroll
          for (int h = 0; h < 4; ++h) pk[h] = (_Float16)pv[h];
          *(f16x4*)(s_p16 + ln * 66 + s * 4) = pk;
        }
        if (ln == 0) {
          f16x4 mk;
          #pragma unroll
          for (int h = 0; h < 4; ++h) mk[h] = (_Float16)msx[h];
          *(f16x4*)(s_ml + s * 4) = mk;
          if (c == 1) {
            f16x4 lk;
            #pragma unroll
            for (int h = 0; h < 4; ++h) lk[h] = (_Float16)lsx[h];
            *(f16x4*)(s_ml + 64 + s * 4) = lk;
          }
        }
      }
      __syncthreads();

      // --- PV chunk (rescale accumulator, then cnt MFMAs) ---
      {
        #pragma unroll
        for (int j2 = 0; j2 < 4; ++j2) {
          float mc = (float)s_ml[(oct * 4 + j2) * 4 + wv];
          float f = __builtin_exp2f(mprev[j2] - mc);
          oaccA[j2] *= f; oaccB[j2] *= f; mprev[j2] = mc;
        }
        #pragma unroll
        for (int i = 0; i < 8; ++i) {
          if (i >= cnt) break;
          _Float16 pw = s_p16[i * 66 + lr * 4 + wv];
          f16x8 frag;
          if (oct < 3) {
            f16x8 rv = *(const f16x8*)(sRAW + i * 1088 + lr * 68 + ((oct << 4) ^ ((i & 3) << 4)));
            #pragma unroll
            for (int k = 0; k < 8; ++k) frag[k] = rv[k] * pw;
          } else {
            frag = ZERO8F; frag[0] = pw;
          }
          if (i & 1) oaccB = MFH(frag, vbF, oaccB);
          else       oaccA = MFH(frag, vbF, oaccA);
        }
      }
      __syncthreads();
    }

    // --- normalize + att16 write ---
    #pragma unroll
    for (int j2 = 0; j2 < 4; ++j2) {
      float lf = (float)s_ml[64 + (oct * 4 + j2) * 4 + wv];
      s_att16[(oct * 4 + j2) * 68 + wv * 16 + lr] =
          (_Float16)((oaccA[j2] + oaccB[j2]) * __builtin_amdgcn_rcpf(lf));
    }
    __syncthreads();

    // --- o-GEMM -> u[:, 64+side*64]; prestage enemy c0 during side0 ---
    {
      f16x8 a0 = *(const f16x8*)(s_att16 + lr * 68 + oct * 8);
      f16x8 a1 = *(const f16x8*)(s_att16 + lr * 68 + 32 + oct * 8);
      f16x8 b0 = *(const f16x8*)(woT + (wv * 16 + lr) * 64 + oct * 8);
      f16x8 b1 = *(const f16x8*)(woT + (wv * 16 + lr) * 64 + 32 + oct * 8);
      f32x4 oa = ZERO4;
      oa = MFH(a0, b0, oa);
      oa = MFH(a1, b1, oa);
      #pragma unroll
      for (int j = 0; j < 4; ++j)
        s_u16[(oct * 4 + j) * 196 + 64 + side * 64 + wv * 16 + lr] = (_Float16)oa[j];
      if (side == 0) stage(enemy_raw, 384, 0, 8);
    }
    __syncthreads();
  }

  // ---------------- phase 4: GRU (f16 MFMA, hidden from global) ------------
  {
    const _Float16* ihT = (const _Float16*)((const char*)ws + OFF_GIH);
    const _Float16* hhT = (const _Float16*)((const char*)ws + OFF_GHH);
    const float* gbS = (const float*)((const char*)ws + OFF_GBS);
    const float* gbH = (const float*)((const char*)ws + OFF_GBH);
    const float* hg = hidden + (size_t)bs0 * 64;

    f16x8 hf0, hf1;
    {
      float4 ha = *(const float4*)(hg + lr * 64 + oct * 8);
      float4 hb = *(const float4*)(hg + lr * 64 + oct * 8 + 4);
      float4 hc = *(const float4*)(hg + lr * 64 + 32 + oct * 8);
      float4 hd = *(const float4*)(hg + lr * 64 + 32 + oct * 8 + 4);
      hf0[0]=(_Float16)ha.x; hf0[1]=(_Float16)ha.y; hf0[2]=(_Float16)ha.z; hf0[3]=(_Float16)ha.w;
      hf0[4]=(_Float16)hb.x; hf0[5]=(_Float16)hb.y; hf0[6]=(_Float16)hb.z; hf0[7]=(_Float16)hb.w;
      hf1[0]=(_Float16)hc.x; hf1[1]=(_Float16)hc.y; hf1[2]=(_Float16)hc.z; hf1[3]=(_Float16)hc.w;
      hf1[4]=(_Float16)hd.x; hf1[5]=(_Float16)hd.y; hf1[6]=(_Float16)hd.z; hf1[7]=(_Float16)hd.w;
    }
    const int c0 = wv * 16 + lr;
    float hv4[4];
    #pragma unroll
    for (int j = 0; j < 4; ++j) hv4[j] = hg[(oct * 4 + j) * 64 + c0];

    f32x4 aX0 = ZERO4, aX1 = ZERO4, aX2 = ZERO4, aH2 = ZERO4;
    #pragma unroll
    for (int st = 0; st < 6; ++st) {
      f16x8 uf = *(const f16x8*)(s_u16 + lr * 196 + st * 32 + oct * 8);
      f16x8 b0 = *(const f16x8*)(ihT + ((wv    ) * 16 + lr) * 192 + st * 32 + oct * 8);
      f16x8 b1 = *(const f16x8*)(ihT + ((wv + 4) * 16 + lr) * 192 + st * 32 + oct * 8);
      f16x8 b2 = *(const f16x8*)(ihT + ((wv + 8) * 16 + lr) * 192 + st * 32 + oct * 8);
      aX0 = MFH(uf, b0, aX0);
      aX1 = MFH(uf, b1, aX1);
      aX2 = MFH(uf, b2, aX2);
    }
    #pragma unroll
    for (int st = 0; st < 2; ++st) {
      f16x8 hf = st ? hf1 : hf0;
      f16x8 b0 = *(const f16x8*)(hhT + ((wv    ) * 16 + lr) * 64 + st * 32 + oct * 8);
      f16x8 b1 = *(const f16x8*)(hhT + ((wv + 4) * 16 + lr) * 64 + st * 32 + oct * 8);
      f16x8 b2 = *(const f16x8*)(hhT + ((wv + 8) * 16 + lr) * 64 + st * 32 + oct * 8);
      aX0 = MFH(hf, b0, aX0);
      aX1 = MFH(hf, b1, aX1);
      aH2 = MFH(hf, b2, aH2);
    }
    float bb0 = gbS[c0], bb1 = gbS[c0 + 64], bb2 = gbS[c0 + 128], bbh = gbH[c0];
    #pragma unroll
    for (int j = 0; j < 4; ++j) {
      int row = oct * 4 + j;
      float xr = aX0[j] + bb0;
      float xz = aX1[j] + bb1;
      float xn = aX2[j] + bb2;
      float hn = aH2[j] + bbh;
      float r  = __builtin_amdgcn_rcpf(1.f + __builtin_exp2f(-xr * LOG2E));
      float zg = __builtin_amdgcn_rcpf(1.f + __builtin_exp2f(-xz * LOG2E));
      float ta = xn + r * hn;
      float nc = 1.f - 2.f * __builtin_amdgcn_rcpf(1.f + __builtin_exp2f(2.f * LOG2E * ta));
      s_z16[row * 68 + c0] = (_Float16)((1.f - zg) * nc + zg * hv4[j]);
    }
  }
  __syncthreads();

  // ---------------- phase 5: fused head GEMM (waves 0,1) -------------------
  {
    const _Float16* bhT = (const _Float16*)((const char*)ws + OFF_BHD);
    if (wv < 2) {
      f16x8 a0 = *(const f16x8*)(s_z16 + lr * 68 + oct * 8);
      f16x8 a1 = *(const f16x8*)(s_z16 + lr * 68 + 32 + oct * 8);
      f16x8 b0 = *(const f16x8*)(bhT + (wv * 16 + lr) * 64 + oct * 8);
      f16x8 b1 = *(const f16x8*)(bhT + (wv * 16 + lr) * 64 + 32 + oct * 8);
      f32x4 td = ZERO4;
      td = MFH(a0, b0, td);
      td = MFH(a1, b1, td);
      const int col = wv * 16 + lr;
      #pragma unroll
      for (int j = 0; j < 4; ++j) {
        int row = oct * 4 + j;
        if (col < 25)      s_t16[row * 26 + col] = (_Float16)td[j];
        else if (col < 31) s_q[row * 22 + (col - 25)] = td[j] + bm[col - 25];
      }
    }
  }
  __syncthreads();
  // shoot logits: enemy raw from global (L3) + t
  {
    const float* er = enemy_raw + (size_t)(bs0 + s) * 384 + ln * 24;
    const _Float16* tp = s_t16 + s * 26;
    float acc2 = (float)tp[24];
    #pragma unroll
    for (int k4 = 0; k4 < 6; ++k4) {
      float4 r4 = *(const float4*)(er + k4 * 4);
      acc2 += r4.x * (float)tp[k4*4]   + r4.y * (float)tp[k4*4+1]
            + r4.z * (float)tp[k4*4+2] + r4.w * (float)tp[k4*4+3];
    }
    s_q[s * 22 + 6 + ln] = acc2;
  }
  __syncthreads();
  // coalesced output tail
  for (int i = tid; i < 352; i += 256)
    out[(size_t)bs0 * 22 + i] = s_q[i];
  for (int i = tid; i < 1024; i += 256)
    out[(size_t)BN * 22 + (size_t)bs0 * 64 + i] = (float)s_z16[(i >> 6) * 68 + (i & 63)];
}

// ============================================================= launch =======
extern "C" void kernel_launch(void* const* d_in, const int* in_sizes, int n_in,
                              void* d_out, int out_size, void* d_ws, size_t ws_size,
                              hipStream_t stream) {
  (void)n_in; (void)out_size; (void)ws_size;
  const float* own_raw   = (const float*)d_in[0];
  const float* ally_raw  = (const float*)d_in[1];
  const float* enemy_raw = (const float*)d_in[2];
  const float* hidden    = (const float*)d_in[3];
  const float* hyp_W1    = (const float*)d_in[4];
  const float* hyp_b1    = (const float*)d_in[5];
  const float* hyp_W2    = (const float*)d_in[6];
  const float* hyp_b2    = (const float*)d_in[7];
  const float* Wa        = (const float*)d_in[8];
  const float* ba        = (const float*)d_in[9];
  const float* We        = (const float*)d_in[10];
  const float* be        = (const float*)d_in[11];
  const float* aWq       = (const float*)d_in[12];
  const float* aWk       = (const float*)d_in[13];
  const float* aWv       = (const float*)d_in[14];
  const float* aWo       = (const float*)d_in[15];
  const float* eWq       = (const float*)d_in[16];
  const float* eWk       = (const float*)d_in[17];
  const float* eWv       = (const float*)d_in[18];
  const float* eWo       = (const float*)d_in[19];
  const float* gWih      = (const float*)d_in[20];
  const float* gWhh      = (const float*)d_in[21];
  const float* gbih      = (const float*)d_in[22];
  const float* gbhh      = (const float*)d_in[23];
  const float* Wm        = (const float*)d_in[24];
  const float* bm        = (const float*)d_in[25];
  const float* WzK       = (const float*)d_in[26];
  const float* WEK       = (const float*)d_in[27];
  int BN = in_sizes[0] / 40;
  int blocks = BN / TB;

  hipLaunchKernelGGL(prep_kernel, dim3(53), dim3(256), 0, stream,
                     hyp_W1, hyp_b1, hyp_W2, hyp_b2, Wa, ba, We, be,
                     aWq, aWk, aWv, aWo, eWq, eWk, eWv, eWo,
                     gWih, gWhh, gbih, gbhh, WzK, WEK, Wm, d_ws);
  hipLaunchKernelGGL(agent_kernel, dim3(blocks), dim3(256), 0, stream,
                     own_raw, ally_raw, enemy_raw, hidden, bm,
                     d_ws, (float*)d_out, BN);
}

// Round 10
// 206.869 us; speedup vs baseline: 1.0686x; 1.0686x over previous
//
#include <hip/hip_runtime.h>
#include <hip/hip_bf16.h>
#include <math.h>

#define TB 16
#define LOG2E 1.44269504f

typedef float f32x4 __attribute__((ext_vector_type(4)));
typedef _Float16 f16x8 __attribute__((ext_vector_type(8)));
typedef _Float16 f16x4 __attribute__((ext_vector_type(4)));
typedef _Float16 f16x2 __attribute__((ext_vector_type(2)));
typedef unsigned int u32x4 __attribute__((ext_vector_type(4)));

// ---------------- ws layout (bytes), all weight mats f16 [col][k] -----------
#define OFF_W1T  344064
#define OFF_WOA  352256   // [64][64] = aWo^T
#define OFF_WOE  360448   // [64][64] = eWo^T
#define OFF_VBA  368640   // [64h][32k] = We@Wv fused (k=24 bias row)
#define OFF_VBE  372736
#define OFF_GA   376832   // [128][64]
#define OFF_GE   393216
#define OFF_GIH  409600
#define OFF_GHH  483328
#define OFF_GBS  507904
#define OFF_GBH  508672
#define OFF_BHD  508928

#define MFH(a, b, c) __builtin_amdgcn_mfma_f32_16x16x32_f16((a), (b), (c), 0, 0, 0)

__device__ inline f16x2 u2h(unsigned u) {
  union { unsigned x; f16x2 h; } c; c.x = u; return c.h;
}
__device__ inline float dot2(f16x2 a, f16x2 b, float c) {
#if __has_builtin(__builtin_amdgcn_fdot2)
  return __builtin_amdgcn_fdot2(a, b, c, false);
#else
  return c + (float)a[0] * (float)b[0] + (float)a[1] * (float)b[1];
#endif
}

// ============================================================= prep =========
__global__ __launch_bounds__(256)
void prep_kernel(const float* __restrict__ hyp_W1, const float* __restrict__ hyp_b1,
                 const float* __restrict__ hyp_W2, const float* __restrict__ hyp_b2,
                 const float* __restrict__ Wa, const float* __restrict__ ba,
                 const float* __restrict__ We, const float* __restrict__ be,
                 const float* __restrict__ aWq, const float* __restrict__ aWk,
                 const float* __restrict__ aWv, const float* __restrict__ aWo,
                 const float* __restrict__ eWq, const float* __restrict__ eWk,
                 const float* __restrict__ eWv, const float* __restrict__ eWo,
                 const float* __restrict__ gWih, const float* __restrict__ gWhh,
                 const float* __restrict__ gbih, const float* __restrict__ gbhh,
                 const float* __restrict__ WzK, const float* __restrict__ WEK,
                 const float* __restrict__ Wm,
                 void* __restrict__ ws)
{
  const int b = blockIdx.x, t = threadIdx.x;
  if (b < 42) {
    _Float16* o = (_Float16*)ws;
    for (int i = t; i < 4096; i += 256) {
      int h = i >> 6, k = i & 63;
      float v;
      if (b < 40)       v = hyp_W2[(size_t)k * 2628 + b * 64 + h];
      else if (b == 40) v = hyp_W2[(size_t)k * 2628 + 2560 + h];
      else              v = (k < 40) ? hyp_b2[k * 64 + h]
                             : (k == 40 ? hyp_b2[2560 + h] : 0.0f);
      o[b * 4096 + i] = (_Float16)v;
    }
  } else if (b == 42) {
    _Float16* o = (_Float16*)((char*)ws + OFF_W1T);
    for (int i = t; i < 4096; i += 256) {
      int h = i >> 6, k = i & 63;
      float v = (k < 40) ? hyp_W1[k * 64 + h] : (k == 40 ? hyp_b1[h] : 0.0f);
      o[i] = (_Float16)v;
    }
  } else if (b == 43 || b == 44) {
    const float* M = (b == 43) ? aWo : eWo;
    _Float16* o = (_Float16*)((char*)ws + (b == 43 ? OFF_WOA : OFF_WOE));
    for (int i = t; i < 4096; i += 256)
      o[i] = (_Float16)M[(i & 63) * 64 + (i >> 6)];
  } else if (b == 45 || b == 46) {
    const float* Wemb = (b == 45) ? Wa : We;
    const float* bemb = (b == 45) ? ba : be;
    const float* Wv   = (b == 45) ? aWv : eWv;
    _Float16* o = (_Float16*)((char*)ws + (b == 45 ? OFF_VBA : OFF_VBE));
    for (int i = t; i < 2048; i += 256) {
      int h = i >> 5, k = i & 31;
      float v = 0.f;
      if (k < 24)       { for (int d = 0; d < 64; ++d) v += Wemb[k * 64 + d] * Wv[d * 64 + h]; }
      else if (k == 24) { for (int d = 0; d < 64; ++d) v += bemb[d] * Wv[d * 64 + h]; }
      o[i] = (_Float16)v;
    }
  } else if (b == 47 || b == 48) {
    const float* Wemb = (b == 47) ? Wa : We;
    const float* bemb = (b == 47) ? ba : be;
    const float* Wk   = (b == 47) ? aWk : eWk;
    const float* Wq   = (b == 47) ? aWq : eWq;
    _Float16* o = (_Float16*)((char*)ws + (b == 47 ? OFF_GA : OFF_GE));
    __shared__ float sKb[25 * 64];
    for (int i = t; i < 1600; i += 256) {
      int k = i >> 6, c = i & 63;
      float v = 0.f;
      if (k < 24)  { for (int d = 0; d < 64; ++d) v += Wemb[k * 64 + d] * Wk[d * 64 + c]; }
      else         { for (int d = 0; d < 64; ++d) v += bemb[d] * Wk[d * 64 + c]; }
      sKb[i] = v;
    }
    __syncthreads();
    for (int i = t; i < 8192; i += 256) {
      int col = i >> 6, d = i & 63;
      int h = col >> 5, kk = col & 31;
      float v = 0.f;
      if (kk < 25)
        for (int dh = 0; dh < 16; ++dh)
          v += Wq[d * 64 + h * 16 + dh] * sKb[kk * 64 + h * 16 + dh];
      o[i] = (_Float16)(v * 0.25f * LOG2E);
    }
  } else if (b == 49) {
    _Float16* o = (_Float16*)((char*)ws + OFF_GIH);
    for (int i = t; i < 36864; i += 256) {
      int d = i / 192, c = i - d * 192;
      o[c * 192 + d] = (_Float16)gWih[i];
    }
  } else if (b == 50) {
    _Float16* o = (_Float16*)((char*)ws + OFF_GHH);
    for (int i = t; i < 12288; i += 256) {
      int d = i / 192, c = i - d * 192;
      o[c * 64 + d] = (_Float16)gWhh[i];
    }
  } else if (b == 51) {
    float* gbS = (float*)((char*)ws + OFF_GBS);
    float* gbH = (float*)((char*)ws + OFF_GBH);
    if (t < 192) gbS[t] = gbih[t] + (t < 128 ? gbhh[t] : 0.0f);
    if (t < 64)  gbH[t] = gbhh[128 + t];
  } else if (b == 52) { // head B-matrix
    __shared__ float sWsK[24 * 64];
    __shared__ float sbw[64];
    _Float16* o = (_Float16*)((char*)ws + OFF_BHD);
    for (int i = t; i < 1536; i += 256) {
      int j = i >> 6, h = i & 63;
      float v = 0.f;
      for (int c = 0; c < 64; ++c) v += We[j * 64 + c] * WEK[c * 64 + h];
      sWsK[i] = v;
    }
    if (t < 64) {
      float v = 0.f;
      for (int c = 0; c < 64; ++c) v += be[c] * WEK[c * 64 + t];
      sbw[t] = v;
    }
    __syncthreads();
    for (int i = t; i < 2048; i += 256) {
      int col = i >> 6, c = i & 63;
      float v = 0.f;
      if (col < 24)       { for (int d = 0; d < 64; ++d) v += WzK[c * 64 + d] * sWsK[col * 64 + d]; }
      else if (col == 24) { for (int d = 0; d < 64; ++d) v += WzK[c * 64 + d] * sbw[d]; }
      else if (col < 31)  v = Wm[c * 6 + (col - 25)];
      o[i] = (_Float16)v;
    }
  }
}

// ============================================================= main =========
__global__ __launch_bounds__(256, 5)
void agent_kernel(
    const float* __restrict__ own_raw, const float* __restrict__ ally_raw,
    const float* __restrict__ enemy_raw, const float* __restrict__ hidden,
    const float* __restrict__ bm,
    const void* __restrict__ ws,
    float* __restrict__ out, int BN)
{
  // LDS = 6272 (u16) + 8704 (raw chunk) + 5472 (R2 union) = 20448 B
  // actual occupancy: min(LDS 163840/20480 = 8, VGPR 512/actual) blocks/CU
  __shared__ __align__(16) char s_all[20448];
  _Float16* s_u16 = (_Float16*)s_all;            // [16][196]
  char*     sRAW  = s_all + 6272;                // [8][16][34] f16, 16B-chunk XOR by (n&3)
  char*     sR2   = s_all + 14976;
  // ph0-2
  _Float16* s_own16 = (_Float16*)sR2;            // [16][52]
  _Float16* s_ownT  = (_Float16*)(sR2 + 1664);   // [40][16]
  _Float16* s_h116  = (_Float16*)(sR2 + 2944);   // [16][68]
  // ph3
  _Float16* s_w16 = (_Float16*)sR2;              // [16][130]
  _Float16* s_p16 = (_Float16*)(sR2 + 4160);     // [8][66]
  _Float16* s_ml  = (_Float16*)(sR2 + 5216);     // m[16][4] @0, l[16][4] @64
  _Float16* s_att16 = (_Float16*)sR2;            // [16][68] (post-PV, w16 dead)
  // ph4+
  _Float16* s_z16 = (_Float16*)sR2;              // [16][68]
  _Float16* s_t16 = (_Float16*)(sR2 + 2176);     // [16][26]
  float*    s_q   = (float*)(sR2 + 3008);        // [16][22]

  const int tid = threadIdx.x;
  const int bs0 = blockIdx.x * TB;
  const int s   = tid >> 4;
  const int ln  = tid & 15;
  const int l   = tid & 63;
  const int wv  = tid >> 6;
  const int lr  = l & 15;
  const int oct = l >> 4;

  const f16x8 ZERO8F = {0,0,0,0,0,0,0,0};
  f16x8 ONE8F = ZERO8F; ONE8F[0] = (_Float16)1.0f;
  const f32x4 ZERO4 = {0.f, 0.f, 0.f, 0.f};
  const float MASKED = -30000.0f;   // exactly f16-representable
  const float PHANT  = -31008.0f;   // < MASKED, f16-safe magnitude

  auto stage = [&](const float* rawg, int rstr, int base, int cnt) {
    for (int i = tid; i < cnt * 192; i += 256) {
      int nn = i / 192, r = i - nn * 192, s2 = r / 12, cc = r - s2 * 12;
      float2 v = *(const float2*)(rawg + (size_t)(bs0 + s2) * rstr + (base + nn) * 24 + cc * 2);
      f16x2 pk; pk[0] = (_Float16)v.x; pk[1] = (_Float16)v.y;
      int byte = cc * 4;
      int sw = ((((byte >> 4) ^ (nn & 3)) << 4) | (byte & 15));
      *(f16x2*)(sRAW + nn * 1088 + s2 * 68 + sw) = pk;
    }
  };

  // ---------------- phase 0: stage own (f16 + f16-T) + ALLY chunk0 ---------
  for (int i = tid; i < 320; i += 256) {
    int ss = i / 20, c = i - ss * 20;
    float2 v = *(const float2*)(own_raw + (size_t)(bs0 + ss) * 40 + c * 2);
    f16x2 pk; pk[0] = (_Float16)v.x; pk[1] = (_Float16)v.y;
    *(f16x2*)(s_own16 + ss * 52 + c * 2) = pk;
  }
  for (int i = tid; i < 640; i += 256) {       // ownT[f][s] f16
    int f = i >> 4, s2 = i & 15;
    s_ownT[i] = (_Float16)own_raw[(size_t)(bs0 + s2) * 40 + f];
  }
  stage(ally_raw, 360, 0, 8);
  __syncthreads();

  // ---------------- phase 1: h1 = relu(own @ W1 + b1) ----------------
  {
    const _Float16* w1t = (const _Float16*)((const char*)ws + OFF_W1T);
    f16x8 a0 = *(const f16x8*)(s_own16 + lr * 52 + oct * 8);
    f16x8 a1;
    if (oct == 0)      a1 = *(const f16x8*)(s_own16 + lr * 52 + 32);
    else if (oct == 1) a1 = ONE8F;
    else               a1 = ZERO8F;
    f16x8 b0 = *(const f16x8*)(w1t + (wv * 16 + lr) * 64 + oct * 8);
    f16x8 b1 = *(const f16x8*)(w1t + (wv * 16 + lr) * 64 + 32 + oct * 8);
    f32x4 acc = ZERO4;
    acc = MFH(a0, b0, acc);
    acc = MFH(a1, b1, acc);
    #pragma unroll
    for (int j = 0; j < 4; ++j)
      s_h116[(oct * 4 + j) * 68 + wv * 16 + lr] = (_Float16)fmaxf(acc[j], 0.f);
  }
  __syncthreads();

  // ---------------- phase 2: own_e, scale-in-accumulator -------------------
  {
    const _Float16* bb = (const _Float16*)ws + (size_t)(wv * 16 + lr) * 64 + oct * 8;
    f16x8 h0f = *(const f16x8*)(s_h116 + lr * 68 + oct * 8);
    f16x8 h1f = *(const f16x8*)(s_h116 + lr * 68 + 32 + oct * 8);
    f32x4 acc = ZERO4;
    #pragma unroll 4
    for (int f = 0; f < 40; ++f) {
      f16x8 b0 = *(const f16x8*)(bb + (size_t)f * 4096);
      f16x8 b1 = *(const f16x8*)(bb + (size_t)f * 4096 + 32);
      f32x4 y = MFH(h0f, b0, ZERO4);
      y = MFH(h1f, b1, y);
      f16x4 ovh = *(const f16x4*)(s_ownT + f * 16 + oct * 4);
      #pragma unroll
      for (int j = 0; j < 4; ++j) acc[j] += (float)ovh[j] * y[j];
    }
    f32x4 accD = ZERO4;
    {
      f16x8 b0 = *(const f16x8*)(bb + (size_t)40 * 4096);
      f16x8 b1 = *(const f16x8*)(bb + (size_t)40 * 4096 + 32);
      accD = MFH(h0f, b0, accD);
      accD = MFH(h1f, b1, accD);
    }
    {
      f16x8 b0 = *(const f16x8*)(bb + (size_t)41 * 4096);
      f16x8 b1 = *(const f16x8*)(bb + (size_t)41 * 4096 + 32);
      f16x8 a0 = *(const f16x8*)(s_own16 + lr * 52 + oct * 8);
      f16x8 a1;
      if (oct == 0)      a1 = *(const f16x8*)(s_own16 + lr * 52 + 32);
      else if (oct == 1) a1 = ONE8F;
      else               a1 = ZERO8F;
      accD = MFH(a0, b0, accD);
      accD = MFH(a1, b1, accD);
    }
    #pragma unroll
    for (int j = 0; j < 4; ++j)
      s_u16[(oct * 4 + j) * 196 + wv * 16 + lr] = (_Float16)(acc[j] + accD[j]);
  }
  __syncthreads();

  // ---------------- phase 3: MHA, chunked online-softmax -------------------
  for (int side = 0; side < 2; ++side) {
    const int n_ent = side ? 16 : 15;
    const int rstr  = side ? 384 : 360;
    const float* rawg = side ? enemy_raw : ally_raw;
    const _Float16* woT = (const _Float16*)((const char*)ws + (side ? OFF_WOE : OFF_WOA));
    const _Float16* vbT = (const _Float16*)((const char*)ws + (side ? OFF_VBE : OFF_VBA));
    const _Float16* gT  = (const _Float16*)((const char*)ws + (side ? OFF_GE  : OFF_GA));

    // --- w = own_e @ G -> w16 ---
    {
      f16x8 a0 = *(const f16x8*)(s_u16 + lr * 196 + oct * 8);
      f16x8 a1 = *(const f16x8*)(s_u16 + lr * 196 + 32 + oct * 8);
      #pragma unroll
      for (int t2 = 0; t2 < 2; ++t2) {
        int col = wv * 32 + t2 * 16 + lr;
        f16x8 b0 = *(const f16x8*)(gT + col * 64 + oct * 8);
        f16x8 b1 = *(const f16x8*)(gT + col * 64 + 32 + oct * 8);
        f32x4 acc = ZERO4;
        acc = MFH(a0, b0, acc);
        acc = MFH(a1, b1, acc);
        #pragma unroll
        for (int j = 0; j < 4; ++j)
          s_w16[(oct * 4 + j) * 130 + col] = (_Float16)acc[j];
      }
    }
    __syncthreads();

    float msx[4] = {-INFINITY, -INFINITY, -INFINITY, -INFINITY};
    float lsx[4] = {0.f, 0.f, 0.f, 0.f};
    f32x4 oaccA = ZERO4, oaccB = ZERO4;
    float mprev[4] = {-INFINITY, -INFINITY, -INFINITY, -INFINITY};
    f16x8 vbF = *(const f16x8*)(vbT + (wv * 16 + lr) * 32 + oct * 8);

    for (int c = 0; c < 2; ++c) {
      const int base = c << 3;
      const int cnt  = (n_ent - base < 8) ? (n_ent - base) : 8;
      if (c > 0) {
        stage(rawg, rstr, base, cnt);
        __syncthreads();
      }

      // --- SCORE chunk ---
      {
        float sc[4] = {PHANT, PHANT, PHANT, PHANT};
        if (ln < cnt) {
          const char* rb = sRAW + ln * 1088 + s * 68;
          const int x = (ln & 3) << 4;
          u32x4 c0 = *(const u32x4*)(rb + (0  ^ x));
          u32x4 c1 = *(const u32x4*)(rb + (16 ^ x));
          u32x4 c2 = *(const u32x4*)(rb + (32 ^ x));
          u32x4 orv = c0 | c1 | c2;
          bool msk = (orv[0] | orv[1] | orv[2] | orv[3]) != 0u;
          const _Float16* wp = s_w16 + s * 130;
          #pragma unroll
          for (int h = 0; h < 4; ++h) {
            float a = (float)wp[h * 32 + 24];
            #pragma unroll
            for (int p = 0; p < 4; ++p) {
              a = dot2(u2h(c0[p]), *(const f16x2*)(wp + h * 32 + 2 * p), a);
              a = dot2(u2h(c1[p]), *(const f16x2*)(wp + h * 32 + 8 + 2 * p), a);
              a = dot2(u2h(c2[p]), *(const f16x2*)(wp + h * 32 + 16 + 2 * p), a);
            }
            sc[h] = msk ? a : MASKED;
          }
        }
        float mx[4];
        #pragma unroll
        for (int h = 0; h < 4; ++h) mx[h] = sc[h];
        #pragma unroll
        for (int d = 1; d < 8; d <<= 1) {
          #pragma unroll
          for (int h = 0; h < 4; ++h) mx[h] = fmaxf(mx[h], __shfl_xor(mx[h], d));
        }
        float pv[4], ps[4], mn[4];
        #pragma unroll
        for (int h = 0; h < 4; ++h) {
          mn[h] = (float)(_Float16)fmaxf(msx[h], mx[h]);   // quantized running max
          pv[h] = __builtin_exp2f(sc[h] - mn[h]);
          ps[h] = pv[h];
        }
        #pragma unroll
        for (int d = 1; d < 8; d <<= 1) {
          #pragma unroll
          for (int h = 0; h < 4; ++h) ps[h] += __shfl_xor(ps[h], d);
        }
        #pragma unroll
        for (int h = 0; h < 4; ++h) {
          lsx[h] = lsx[h] * __builtin_exp2f(msx[h] - mn[h]) + ps[h];
          msx[h] = mn[h];
        }
        if (ln < 8) {
          f16x4 pk;
          #pragma unroll
          for (int h = 0; h < 4; ++h) pk[h] = (_Float16)pv[h];
          *(f16x4*)(s_p16 + ln * 66 + s * 4) = pk;
        }
        if (ln == 0) {
          f16x4 mk;
          #pragma unroll
          for (int h = 0; h < 4; ++h) mk[h] = (_Float16)msx[h];
          *(f16x4*)(s_ml + s * 4) = mk;
          if (c == 1) {
            f16x4 lk;
            #pragma unroll
            for (int h = 0; h < 4; ++h) lk[h] = (_Float16)lsx[h];
            *(f16x4*)(s_ml + 64 + s * 4) = lk;
          }
        }
      }
      __syncthreads();

      // --- PV chunk (rescale accumulator, then cnt MFMAs) ---
      {
        #pragma unroll
        for (int j2 = 0; j2 < 4; ++j2) {
          float mc = (float)s_ml[(oct * 4 + j2) * 4 + wv];
          float f = __builtin_exp2f(mprev[j2] - mc);
          oaccA[j2] *= f; oaccB[j2] *= f; mprev[j2] = mc;
        }
        #pragma unroll
        for (int i = 0; i < 8; ++i) {
          if (i >= cnt) break;
          _Float16 pw = s_p16[i * 66 + lr * 4 + wv];
          f16x8 frag;
          if (oct < 3) {
            f16x8 rv = *(const f16x8*)(sRAW + i * 1088 + lr * 68 + ((oct << 4) ^ ((i & 3) << 4)));
            #pragma unroll
            for (int k = 0; k < 8; ++k) frag[k] = rv[k] * pw;
          } else {
            frag = ZERO8F; frag[0] = pw;
          }
          if (i & 1) oaccB = MFH(frag, vbF, oaccB);
          else       oaccA = MFH(frag, vbF, oaccA);
        }
      }
      __syncthreads();
    }

    // --- normalize + att16 write ---
    #pragma unroll
    for (int j2 = 0; j2 < 4; ++j2) {
      float lf = (float)s_ml[64 + (oct * 4 + j2) * 4 + wv];
      s_att16[(oct * 4 + j2) * 68 + wv * 16 + lr] =
          (_Float16)((oaccA[j2] + oaccB[j2]) * __builtin_amdgcn_rcpf(lf));
    }
    __syncthreads();

    // --- o-GEMM -> u[:, 64+side*64]; prestage enemy c0 during side0 ---
    {
      f16x8 a0 = *(const f16x8*)(s_att16 + lr * 68 + oct * 8);
      f16x8 a1 = *(const f16x8*)(s_att16 + lr * 68 + 32 + oct * 8);
      f16x8 b0 = *(const f16x8*)(woT + (wv * 16 + lr) * 64 + oct * 8);
      f16x8 b1 = *(const f16x8*)(woT + (wv * 16 + lr) * 64 + 32 + oct * 8);
      f32x4 oa = ZERO4;
      oa = MFH(a0, b0, oa);
      oa = MFH(a1, b1, oa);
      #pragma unroll
      for (int j = 0; j < 4; ++j)
        s_u16[(oct * 4 + j) * 196 + 64 + side * 64 + wv * 16 + lr] = (_Float16)oa[j];
      if (side == 0) stage(enemy_raw, 384, 0, 8);
    }
    __syncthreads();
  }

  // ---------------- phase 4: GRU (f16 MFMA, hidden from global) ------------
  {
    const _Float16* ihT = (const _Float16*)((const char*)ws + OFF_GIH);
    const _Float16* hhT = (const _Float16*)((const char*)ws + OFF_GHH);
    const float* gbS = (const float*)((const char*)ws + OFF_GBS);
    const float* gbH = (const float*)((const char*)ws + OFF_GBH);
    const float* hg = hidden + (size_t)bs0 * 64;

    f16x8 hf0, hf1;
    {
      float4 ha = *(const float4*)(hg + lr * 64 + oct * 8);
      float4 hb = *(const float4*)(hg + lr * 64 + oct * 8 + 4);
      float4 hc = *(const float4*)(hg + lr * 64 + 32 + oct * 8);
      float4 hd = *(const float4*)(hg + lr * 64 + 32 + oct * 8 + 4);
      hf0[0]=(_Float16)ha.x; hf0[1]=(_Float16)ha.y; hf0[2]=(_Float16)ha.z; hf0[3]=(_Float16)ha.w;
      hf0[4]=(_Float16)hb.x; hf0[5]=(_Float16)hb.y; hf0[6]=(_Float16)hb.z; hf0[7]=(_Float16)hb.w;
      hf1[0]=(_Float16)hc.x; hf1[1]=(_Float16)hc.y; hf1[2]=(_Float16)hc.z; hf1[3]=(_Float16)hc.w;
      hf1[4]=(_Float16)hd.x; hf1[5]=(_Float16)hd.y; hf1[6]=(_Float16)hd.z; hf1[7]=(_Float16)hd.w;
    }
    const int c0 = wv * 16 + lr;
    float hv4[4];
    #pragma unroll
    for (int j = 0; j < 4; ++j) hv4[j] = hg[(oct * 4 + j) * 64 + c0];

    f32x4 aX0 = ZERO4, aX1 = ZERO4, aX2 = ZERO4, aH2 = ZERO4;
    #pragma unroll
    for (int st = 0; st < 6; ++st) {
      f16x8 uf = *(const f16x8*)(s_u16 + lr * 196 + st * 32 + oct * 8);
      f16x8 b0 = *(const f16x8*)(ihT + ((wv    ) * 16 + lr) * 192 + st * 32 + oct * 8);
      f16x8 b1 = *(const f16x8*)(ihT + ((wv + 4) * 16 + lr) * 192 + st * 32 + oct * 8);
      f16x8 b2 = *(const f16x8*)(ihT + ((wv + 8) * 16 + lr) * 192 + st * 32 + oct * 8);
      aX0 = MFH(uf, b0, aX0);
      aX1 = MFH(uf, b1, aX1);
      aX2 = MFH(uf, b2, aX2);
    }
    #pragma unroll
    for (int st = 0; st < 2; ++st) {
      f16x8 hf = st ? hf1 : hf0;
      f16x8 b0 = *(const f16x8*)(hhT + ((wv    ) * 16 + lr) * 64 + st * 32 + oct * 8);
      f16x8 b1 = *(const f16x8*)(hhT + ((wv + 4) * 16 + lr) * 64 + st * 32 + oct * 8);
      f16x8 b2 = *(const f16x8*)(hhT + ((wv + 8) * 16 + lr) * 64 + st * 32 + oct * 8);
      aX0 = MFH(hf, b0, aX0);
      aX1 = MFH(hf, b1, aX1);
      aH2 = MFH(hf, b2, aH2);
    }
    float bb0 = gbS[c0], bb1 = gbS[c0 + 64], bb2 = gbS[c0 + 128], bbh = gbH[c0];
    #pragma unroll
    for (int j = 0; j < 4; ++j) {
      int row = oct * 4 + j;
      float xr = aX0[j] + bb0;
      float xz = aX1[j] + bb1;
      float xn = aX2[j] + bb2;
      float hn = aH2[j] + bbh;
      float r  = __builtin_amdgcn_rcpf(1.f + __builtin_exp2f(-xr * LOG2E));
      float zg = __builtin_amdgcn_rcpf(1.f + __builtin_exp2f(-xz * LOG2E));
      float ta = xn + r * hn;
      float nc = 1.f - 2.f * __builtin_amdgcn_rcpf(1.f + __builtin_exp2f(2.f * LOG2E * ta));
      s_z16[row * 68 + c0] = (_Float16)((1.f - zg) * nc + zg * hv4[j]);
    }
  }
  __syncthreads();

  // ---------------- phase 5: fused head GEMM (waves 0,1) -------------------
  {
    const _Float16* bhT = (const _Float16*)((const char*)ws + OFF_BHD);
    if (wv < 2) {
      f16x8 a0 = *(const f16x8*)(s_z16 + lr * 68 + oct * 8);
      f16x8 a1 = *(const f16x8*)(s_z16 + lr * 68 + 32 + oct * 8);
      f16x8 b0 = *(const f16x8*)(bhT + (wv * 16 + lr) * 64 + oct * 8);
      f16x8 b1 = *(const f16x8*)(bhT + (wv * 16 + lr) * 64 + 32 + oct * 8);
      f32x4 td = ZERO4;
      td = MFH(a0, b0, td);
      td = MFH(a1, b1, td);
      const int col = wv * 16 + lr;
      #pragma unroll
      for (int j = 0; j < 4; ++j) {
        int row = oct * 4 + j;
        if (col < 25)      s_t16[row * 26 + col] = (_Float16)td[j];
        else if (col < 31) s_q[row * 22 + (col - 25)] = td[j] + bm[col - 25];
      }
    }
  }
  __syncthreads();
  // shoot logits: enemy raw from global (L3) + t
  {
    const float* er = enemy_raw + (size_t)(bs0 + s) * 384 + ln * 24;
    const _Float16* tp = s_t16 + s * 26;
    float acc2 = (float)tp[24];
    #pragma unroll
    for (int k4 = 0; k4 < 6; ++k4) {
      float4 r4 = *(const float4*)(er + k4 * 4);
      acc2 += r4.x * (float)tp[k4*4]   + r4.y * (float)tp[k4*4+1]
            + r4.z * (float)tp[k4*4+2] + r4.w * (float)tp[k4*4+3];
    }
    s_q[s * 22 + 6 + ln] = acc2;
  }
  __syncthreads();
  // coalesced output tail
  for (int i = tid; i < 352; i += 256)
    out[(size_t)bs0 * 22 + i] = s_q[i];
  for (int i = tid; i < 1024; i += 256)
    out[(size_t)BN * 22 + (size_t)bs0 * 64 + i] = (float)s_z16[(i >> 6) * 68 + (i & 63)];
}

// ============================================================= launch =======
extern "C" void kernel_launch(void* const* d_in, const int* in_sizes, int n_in,
                              void* d_out, int out_size, void* d_ws, size_t ws_size,
                              hipStream_t stream) {
  (void)n_in; (void)out_size; (void)ws_size;
  const float* own_raw   = (const float*)d_in[0];
  const float* ally_raw  = (const float*)d_in[1];
  const float* enemy_raw = (const float*)d_in[2];
  const float* hidden    = (const float*)d_in[3];
  const float* hyp_W1    = (const float*)d_in[4];
  const float* hyp_b1    = (const float*)d_in[5];
  const float* hyp_W2    = (const float*)d_in[6];
  const float* hyp_b2    = (const float*)d_in[7];
  const float* Wa        = (const float*)d_in[8];
  const float* ba        = (const float*)d_in[9];
  const float* We        = (const float*)d_in[10];
  const float* be        = (const float*)d_in[11];
  const float* aWq       = (const float*)d_in[12];
  const float* aWk       = (const float*)d_in[13];
  const float* aWv       = (const float*)d_in[14];
  const float* aWo       = (const float*)d_in[15];
  const float* eWq       = (const float*)d_in[16];
  const float* eWk       = (const float*)d_in[17];
  const float* eWv       = (const float*)d_in[18];
  const float* eWo       = (const float*)d_in[19];
  const float* gWih      = (const float*)d_in[20];
  const float* gWhh      = (const float*)d_in[21];
  const float* gbih      = (const float*)d_in[22];
  const float* gbhh      = (const float*)d_in[23];
  const float* Wm        = (const float*)d_in[24];
  const float* bm        = (const float*)d_in[25];
  const float* WzK       = (const float*)d_in[26];
  const float* WEK       = (const float*)d_in[27];
  int BN = in_sizes[0] / 40;
  int blocks = BN / TB;

  hipLaunchKernelGGL(prep_kernel, dim3(53), dim3(256), 0, stream,
                     hyp_W1, hyp_b1, hyp_W2, hyp_b2, Wa, ba, We, be,
                     aWq, aWk, aWv, aWo, eWq, eWk, eWv, eWo,
                     gWih, gWhh, gbih, gbhh, WzK, WEK, Wm, d_ws);
  hipLaunchKernelGGL(agent_kernel, dim3(blocks), dim3(256), 0, stream,
                     own_raw, ally_raw, enemy_raw, hidden, bm,
                     d_ws, (float*)d_out, BN);
}

// Round 11
// 195.329 us; speedup vs baseline: 1.1317x; 1.0591x over previous
//
#include <hip/hip_runtime.h>
#include <hip/hip_bf16.h>
#include <math.h>

#define TB 16
#define LOG2E 1.44269504f

typedef float f32x4 __attribute__((ext_vector_type(4)));
typedef _Float16 f16x8 __attribute__((ext_vector_type(8)));
typedef _Float16 f16x4 __attribute__((ext_vector_type(4)));
typedef _Float16 f16x2 __attribute__((ext_vector_type(2)));

// ---------------- ws layout (bytes), all weight mats f16 [col][k] -----------
#define OFF_W1T  344064
#define OFF_WOA  352256   // [64][64] = aWo^T
#define OFF_WOE  360448   // [64][64] = eWo^T
#define OFF_VBA  368640   // [64h][32k] = We@Wv fused (k=24 bias row)
#define OFF_VBE  372736
#define OFF_GA   376832   // [128][64]
#define OFF_GE   393216
#define OFF_GIH  409600
#define OFF_GHH  483328
#define OFF_GBS  507904
#define OFF_GBH  508672
#define OFF_BHD  508928

#define MFH(a, b, c) __builtin_amdgcn_mfma_f32_16x16x32_f16((a), (b), (c), 0, 0, 0)

__device__ inline float dot2(f16x2 a, f16x2 b, float c) {
#if __has_builtin(__builtin_amdgcn_fdot2)
  return __builtin_amdgcn_fdot2(a, b, c, false);
#else
  return c + (float)a[0] * (float)b[0] + (float)a[1] * (float)b[1];
#endif
}

// ============================================================= prep =========
__global__ __launch_bounds__(256)
void prep_kernel(const float* __restrict__ hyp_W1, const float* __restrict__ hyp_b1,
                 const float* __restrict__ hyp_W2, const float* __restrict__ hyp_b2,
                 const float* __restrict__ Wa, const float* __restrict__ ba,
                 const float* __restrict__ We, const float* __restrict__ be,
                 const float* __restrict__ aWq, const float* __restrict__ aWk,
                 const float* __restrict__ aWv, const float* __restrict__ aWo,
                 const float* __restrict__ eWq, const float* __restrict__ eWk,
                 const float* __restrict__ eWv, const float* __restrict__ eWo,
                 const float* __restrict__ gWih, const float* __restrict__ gWhh,
                 const float* __restrict__ gbih, const float* __restrict__ gbhh,
                 const float* __restrict__ WzK, const float* __restrict__ WEK,
                 const float* __restrict__ Wm,
                 void* __restrict__ ws)
{
  const int b = blockIdx.x, t = threadIdx.x;
  if (b < 42) {
    _Float16* o = (_Float16*)ws;
    for (int i = t; i < 4096; i += 256) {
      int h = i >> 6, k = i & 63;
      float v;
      if (b < 40)       v = hyp_W2[(size_t)k * 2628 + b * 64 + h];
      else if (b == 40) v = hyp_W2[(size_t)k * 2628 + 2560 + h];
      else              v = (k < 40) ? hyp_b2[k * 64 + h]
                             : (k == 40 ? hyp_b2[2560 + h] : 0.0f);
      o[b * 4096 + i] = (_Float16)v;
    }
  } else if (b == 42) {
    _Float16* o = (_Float16*)((char*)ws + OFF_W1T);
    for (int i = t; i < 4096; i += 256) {
      int h = i >> 6, k = i & 63;
      float v = (k < 40) ? hyp_W1[k * 64 + h] : (k == 40 ? hyp_b1[h] : 0.0f);
      o[i] = (_Float16)v;
    }
  } else if (b == 43 || b == 44) {
    const float* M = (b == 43) ? aWo : eWo;
    _Float16* o = (_Float16*)((char*)ws + (b == 43 ? OFF_WOA : OFF_WOE));
    for (int i = t; i < 4096; i += 256)
      o[i] = (_Float16)M[(i & 63) * 64 + (i >> 6)];
  } else if (b == 45 || b == 46) {
    const float* Wemb = (b == 45) ? Wa : We;
    const float* bemb = (b == 45) ? ba : be;
    const float* Wv   = (b == 45) ? aWv : eWv;
    _Float16* o = (_Float16*)((char*)ws + (b == 45 ? OFF_VBA : OFF_VBE));
    for (int i = t; i < 2048; i += 256) {
      int h = i >> 5, k = i & 31;
      float v = 0.f;
      if (k < 24)       { for (int d = 0; d < 64; ++d) v += Wemb[k * 64 + d] * Wv[d * 64 + h]; }
      else if (k == 24) { for (int d = 0; d < 64; ++d) v += bemb[d] * Wv[d * 64 + h]; }
      o[i] = (_Float16)v;
    }
  } else if (b == 47 || b == 48) {
    const float* Wemb = (b == 47) ? Wa : We;
    const float* bemb = (b == 47) ? ba : be;
    const float* Wk   = (b == 47) ? aWk : eWk;
    const float* Wq   = (b == 47) ? aWq : eWq;
    _Float16* o = (_Float16*)((char*)ws + (b == 47 ? OFF_GA : OFF_GE));
    __shared__ float sKb[25 * 64];
    for (int i = t; i < 1600; i += 256) {
      int k = i >> 6, c = i & 63;
      float v = 0.f;
      if (k < 24)  { for (int d = 0; d < 64; ++d) v += Wemb[k * 64 + d] * Wk[d * 64 + c]; }
      else         { for (int d = 0; d < 64; ++d) v += bemb[d] * Wk[d * 64 + c]; }
      sKb[i] = v;
    }
    __syncthreads();
    for (int i = t; i < 8192; i += 256) {
      int col = i >> 6, d = i & 63;
      int h = col >> 5, kk = col & 31;
      float v = 0.f;
      if (kk < 25)
        for (int dh = 0; dh < 16; ++dh)
          v += Wq[d * 64 + h * 16 + dh] * sKb[kk * 64 + h * 16 + dh];
      o[i] = (_Float16)(v * 0.25f * LOG2E);
    }
  } else if (b == 49) {
    _Float16* o = (_Float16*)((char*)ws + OFF_GIH);
    for (int i = t; i < 36864; i += 256) {
      int d = i / 192, c = i - d * 192;
      o[c * 192 + d] = (_Float16)gWih[i];
    }
  } else if (b == 50) {
    _Float16* o = (_Float16*)((char*)ws + OFF_GHH);
    for (int i = t; i < 12288; i += 256) {
      int d = i / 192, c = i - d * 192;
      o[c * 64 + d] = (_Float16)gWhh[i];
    }
  } else if (b == 51) {
    float* gbS = (float*)((char*)ws + OFF_GBS);
    float* gbH = (float*)((char*)ws + OFF_GBH);
    if (t < 192) gbS[t] = gbih[t] + (t < 128 ? gbhh[t] : 0.0f);
    if (t < 64)  gbH[t] = gbhh[128 + t];
  } else if (b == 52) { // head B-matrix
    __shared__ float sWsK[24 * 64];
    __shared__ float sbw[64];
    _Float16* o = (_Float16*)((char*)ws + OFF_BHD);
    for (int i = t; i < 1536; i += 256) {
      int j = i >> 6, h = i & 63;
      float v = 0.f;
      for (int c = 0; c < 64; ++c) v += We[j * 64 + c] * WEK[c * 64 + h];
      sWsK[i] = v;
    }
    if (t < 64) {
      float v = 0.f;
      for (int c = 0; c < 64; ++c) v += be[c] * WEK[c * 64 + t];
      sbw[t] = v;
    }
    __syncthreads();
    for (int i = t; i < 2048; i += 256) {
      int col = i >> 6, c = i & 63;
      float v = 0.f;
      if (col < 24)       { for (int d = 0; d < 64; ++d) v += WzK[c * 64 + d] * sWsK[col * 64 + d]; }
      else if (col == 24) { for (int d = 0; d < 64; ++d) v += WzK[c * 64 + d] * sbw[d]; }
      else if (col < 31)  v = Wm[c * 6 + (col - 25)];
      o[i] = (_Float16)v;
    }
  }
}

// ============================================================= main =========
__global__ __launch_bounds__(256, 6)
void agent_kernel(
    const float* __restrict__ own_raw, const float* __restrict__ ally_raw,
    const float* __restrict__ enemy_raw, const float* __restrict__ hidden,
    const float* __restrict__ bm,
    const void* __restrict__ ws,
    float* __restrict__ out, int BN)
{
  // LDS = 6272 (u16) + 2176 (hid16) + 6464 (R2 union) = 14912 B
  // -> LDS allows 10 blocks/CU; wave cap (32/CU) allows 8 at 4 waves/block
  __shared__ __align__(16) char s_all[14912];
  _Float16* s_u16   = (_Float16*)s_all;            // [16][196]
  _Float16* s_hid16 = (_Float16*)(s_all + 6272);   // [16][68]
  char*     sR2     = s_all + 8448;
  // ph0-2
  _Float16* s_own16 = (_Float16*)sR2;              // [16][52]
  _Float16* s_ownT  = (_Float16*)(sR2 + 1664);     // [40][16]
  _Float16* s_h116  = (_Float16*)(sR2 + 2944);     // [16][68]
  // ph3
  _Float16* s_w16   = (_Float16*)sR2;              // [16][130]
  _Float16* s_att16 = (_Float16*)sR2;              // [16][68] (post-PV, w16 dead)
  _Float16* s_p16   = (_Float16*)(sR2 + 4160);     // [16][72]
  // ph4+
  _Float16* s_z16   = (_Float16*)sR2;              // [16][68]
  _Float16* s_t16   = (_Float16*)(sR2 + 2176);     // [16][26]
  float*    s_q     = (float*)(sR2 + 3008);        // [16][22]

  const int tid = threadIdx.x;
  const int bs0 = blockIdx.x * TB;
  const int s   = tid >> 4;
  const int ln  = tid & 15;
  const int l   = tid & 63;
  const int wv  = tid >> 6;
  const int lr  = l & 15;
  const int oct = l >> 4;

  const f16x8 ZERO8F = {0,0,0,0,0,0,0,0};
  f16x8 ONE8F = ZERO8F; ONE8F[0] = (_Float16)1.0f;
  const f32x4 ZERO4 = {0.f, 0.f, 0.f, 0.f};

  // ---------------- phase 0: stage own (f16 + f16-T) + hidden --------------
  for (int i = tid; i < 320; i += 256) {
    int ss = i / 20, c = i - ss * 20;
    float2 v = *(const float2*)(own_raw + (size_t)(bs0 + ss) * 40 + c * 2);
    f16x2 pk; pk[0] = (_Float16)v.x; pk[1] = (_Float16)v.y;
    *(f16x2*)(s_own16 + ss * 52 + c * 2) = pk;
  }
  for (int i = tid; i < 640; i += 256) {       // ownT[f][s] f16
    int f = i >> 4, s2 = i & 15;
    s_ownT[i] = (_Float16)own_raw[(size_t)(bs0 + s2) * 40 + f];
  }
  for (int i = tid; i < 512; i += 256) {
    int ss = i >> 5, c = i & 31;
    float2 v = *(const float2*)(hidden + (size_t)(bs0 + ss) * 64 + c * 2);
    f16x2 pk; pk[0] = (_Float16)v.x; pk[1] = (_Float16)v.y;
    *(f16x2*)(s_hid16 + ss * 68 + c * 2) = pk;
  }
  __syncthreads();

  // ---------------- phase 1: h1 = relu(own @ W1 + b1) ----------------
  {
    const _Float16* w1t = (const _Float16*)((const char*)ws + OFF_W1T);
    f16x8 a0 = *(const f16x8*)(s_own16 + lr * 52 + oct * 8);
    f16x8 a1;
    if (oct == 0)      a1 = *(const f16x8*)(s_own16 + lr * 52 + 32);
    else if (oct == 1) a1 = ONE8F;
    else               a1 = ZERO8F;
    f16x8 b0 = *(const f16x8*)(w1t + (wv * 16 + lr) * 64 + oct * 8);
    f16x8 b1 = *(const f16x8*)(w1t + (wv * 16 + lr) * 64 + 32 + oct * 8);
    f32x4 acc = ZERO4;
    acc = MFH(a0, b0, acc);
    acc = MFH(a1, b1, acc);
    #pragma unroll
    for (int j = 0; j < 4; ++j)
      s_h116[(oct * 4 + j) * 68 + wv * 16 + lr] = (_Float16)fmaxf(acc[j], 0.f);
  }
  __syncthreads();

  // ---------------- phase 2: own_e, scale-in-accumulator -------------------
  {
    const _Float16* bb = (const _Float16*)ws + (size_t)(wv * 16 + lr) * 64 + oct * 8;
    f16x8 h0f = *(const f16x8*)(s_h116 + lr * 68 + oct * 8);
    f16x8 h1f = *(const f16x8*)(s_h116 + lr * 68 + 32 + oct * 8);
    f32x4 acc = ZERO4;
    #pragma unroll 4
    for (int f = 0; f < 40; ++f) {
      f16x8 b0 = *(const f16x8*)(bb + (size_t)f * 4096);
      f16x8 b1 = *(const f16x8*)(bb + (size_t)f * 4096 + 32);
      f32x4 y = MFH(h0f, b0, ZERO4);
      y = MFH(h1f, b1, y);
      f16x4 ovh = *(const f16x4*)(s_ownT + f * 16 + oct * 4);
      #pragma unroll
      for (int j = 0; j < 4; ++j) acc[j] += (float)ovh[j] * y[j];
    }
    f32x4 accD = ZERO4;
    {
      f16x8 b0 = *(const f16x8*)(bb + (size_t)40 * 4096);
      f16x8 b1 = *(const f16x8*)(bb + (size_t)40 * 4096 + 32);
      accD = MFH(h0f, b0, accD);
      accD = MFH(h1f, b1, accD);
    }
    {
      f16x8 b0 = *(const f16x8*)(bb + (size_t)41 * 4096);
      f16x8 b1 = *(const f16x8*)(bb + (size_t)41 * 4096 + 32);
      f16x8 a0 = *(const f16x8*)(s_own16 + lr * 52 + oct * 8);
      f16x8 a1;
      if (oct == 0)      a1 = *(const f16x8*)(s_own16 + lr * 52 + 32);
      else if (oct == 1) a1 = ONE8F;
      else               a1 = ZERO8F;
      accD = MFH(a0, b0, accD);
      accD = MFH(a1, b1, accD);
    }
    #pragma unroll
    for (int j = 0; j < 4; ++j)
      s_u16[(oct * 4 + j) * 196 + wv * 16 + lr] = (_Float16)(acc[j] + accD[j]);
  }
  __syncthreads();

  // ---------------- phase 3: MHA (G-trick, raw from global) ----------------
  for (int side = 0; side < 2; ++side) {
    const int n_ent = side ? 16 : 15;
    const int rstr  = side ? 384 : 360;
    const float* rawg = side ? enemy_raw : ally_raw;
    const _Float16* woT = (const _Float16*)((const char*)ws + (side ? OFF_WOE : OFF_WOA));
    const _Float16* vbT = (const _Float16*)((const char*)ws + (side ? OFF_VBE : OFF_VBA));
    const _Float16* gT  = (const _Float16*)((const char*)ws + (side ? OFF_GE  : OFF_GA));

    // --- w = own_e @ G -> w16 ---
    {
      f16x8 a0 = *(const f16x8*)(s_u16 + lr * 196 + oct * 8);
      f16x8 a1 = *(const f16x8*)(s_u16 + lr * 196 + 32 + oct * 8);
      #pragma unroll
      for (int t2 = 0; t2 < 2; ++t2) {
        int col = wv * 32 + t2 * 16 + lr;
        f16x8 b0 = *(const f16x8*)(gT + col * 64 + oct * 8);
        f16x8 b1 = *(const f16x8*)(gT + col * 64 + 32 + oct * 8);
        f32x4 acc = ZERO4;
        acc = MFH(a0, b0, acc);
        acc = MFH(a1, b1, acc);
        #pragma unroll
        for (int j = 0; j < 4; ++j)
          s_w16[(oct * 4 + j) * 130 + col] = (_Float16)acc[j];
      }
    }
    __syncthreads();

    // --- score: thread (s, n=ln); raw from global; 16-lane softmax ---
    {
      float sc0 = -2.0e9f, sc1 = -2.0e9f, sc2 = -2.0e9f, sc3 = -2.0e9f;
      if (ln < n_ent) {
        const float* rp = rawg + (size_t)(bs0 + s) * rstr + ln * 24;
        float r[24];
        #pragma unroll
        for (int k4 = 0; k4 < 6; ++k4)
          *(float4*)(r + k4 * 4) = *(const float4*)(rp + k4 * 4);
        unsigned orv = 0u;
        #pragma unroll
        for (int k = 0; k < 24; ++k) orv |= (r[k] != 0.0f) ? 1u : 0u;
        f16x2 rh[12];
        #pragma unroll
        for (int p = 0; p < 12; ++p) {
          rh[p][0] = (_Float16)r[2 * p];
          rh[p][1] = (_Float16)r[2 * p + 1];
        }
        const _Float16* wp = s_w16 + s * 130;
        float sc[4];
        #pragma unroll
        for (int h = 0; h < 4; ++h) {
          float a = (float)wp[h * 32 + 24];
          #pragma unroll
          for (int p = 0; p < 12; ++p)
            a = dot2(rh[p], *(const f16x2*)(wp + h * 32 + 2 * p), a);
          sc[h] = a;
        }
        if (orv) { sc0 = sc[0]; sc1 = sc[1]; sc2 = sc[2]; sc3 = sc[3]; }
        else     { sc0 = sc1 = sc2 = sc3 = -1.0e9f; }
      }
      float m0 = sc0, m1 = sc1, m2 = sc2, m3 = sc3;
      #pragma unroll
      for (int d = 1; d < 16; d <<= 1) {
        m0 = fmaxf(m0, __shfl_xor(m0, d));
        m1 = fmaxf(m1, __shfl_xor(m1, d));
        m2 = fmaxf(m2, __shfl_xor(m2, d));
        m3 = fmaxf(m3, __shfl_xor(m3, d));
      }
      float p0 = __builtin_exp2f(sc0 - m0);
      float p1 = __builtin_exp2f(sc1 - m1);
      float p2 = __builtin_exp2f(sc2 - m2);
      float p3 = __builtin_exp2f(sc3 - m3);
      float l0 = p0, l1 = p1, l2 = p2, l3 = p3;
      #pragma unroll
      for (int d = 1; d < 16; d <<= 1) {
        l0 += __shfl_xor(l0, d);
        l1 += __shfl_xor(l1, d);
        l2 += __shfl_xor(l2, d);
        l3 += __shfl_xor(l3, d);
      }
      f16x4 pk;
      pk[0] = (_Float16)(p0 * __builtin_amdgcn_rcpf(l0));
      pk[1] = (_Float16)(p1 * __builtin_amdgcn_rcpf(l1));
      pk[2] = (_Float16)(p2 * __builtin_amdgcn_rcpf(l2));
      pk[3] = (_Float16)(p3 * __builtin_amdgcn_rcpf(l3));
      if (ln < n_ent) *(f16x4*)(s_p16 + ln * 72 + s * 4) = pk;
    }
    __syncthreads();

    // --- PV: raw re-read from global (L1/L2-hot), p folded into A-frag ---
    {
      f16x8 vbF = *(const f16x8*)(vbT + (wv * 16 + lr) * 32 + oct * 8);
      const float* rpv = rawg + (size_t)(bs0 + lr) * rstr + oct * 8;
      f32x4 oaccA = ZERO4, oaccB = ZERO4;
      #pragma unroll
      for (int i = 0; i < 16; ++i) {
        if (i >= n_ent) break;
        _Float16 pw = s_p16[i * 72 + lr * 4 + wv];
        f16x8 frag;
        if (oct < 3) {
          float4 a = *(const float4*)(rpv + i * 24);
          float4 b = *(const float4*)(rpv + i * 24 + 4);
          frag[0] = (_Float16)a.x * pw; frag[1] = (_Float16)a.y * pw;
          frag[2] = (_Float16)a.z * pw; frag[3] = (_Float16)a.w * pw;
          frag[4] = (_Float16)b.x * pw; frag[5] = (_Float16)b.y * pw;
          frag[6] = (_Float16)b.z * pw; frag[7] = (_Float16)b.w * pw;
        } else {
          frag = ZERO8F; frag[0] = pw;
        }
        if (i & 1) oaccB = MFH(frag, vbF, oaccB);
        else       oaccA = MFH(frag, vbF, oaccA);
      }
      #pragma unroll
      for (int j = 0; j < 4; ++j)
        s_att16[(oct * 4 + j) * 68 + wv * 16 + lr] = (_Float16)(oaccA[j] + oaccB[j]);
    }
    __syncthreads();

    // --- o-GEMM -> u[:, 64+side*64] ---
    {
      f16x8 a0 = *(const f16x8*)(s_att16 + lr * 68 + oct * 8);
      f16x8 a1 = *(const f16x8*)(s_att16 + lr * 68 + 32 + oct * 8);
      f16x8 b0 = *(const f16x8*)(woT + (wv * 16 + lr) * 64 + oct * 8);
      f16x8 b1 = *(const f16x8*)(woT + (wv * 16 + lr) * 64 + 32 + oct * 8);
      f32x4 oa = ZERO4;
      oa = MFH(a0, b0, oa);
      oa = MFH(a1, b1, oa);
      #pragma unroll
      for (int j = 0; j < 4; ++j)
        s_u16[(oct * 4 + j) * 196 + 64 + side * 64 + wv * 16 + lr] = (_Float16)oa[j];
    }
    __syncthreads();
  }

  // ---------------- phase 4: GRU (f16 MFMA, hid16 LDS) ---------------------
  {
    const _Float16* ihT = (const _Float16*)((const char*)ws + OFF_GIH);
    const _Float16* hhT = (const _Float16*)((const char*)ws + OFF_GHH);
    const float* gbS = (const float*)((const char*)ws + OFF_GBS);
    const float* gbH = (const float*)((const char*)ws + OFF_GBH);
    f32x4 aX0 = ZERO4, aX1 = ZERO4, aX2 = ZERO4, aH2 = ZERO4;
    #pragma unroll
    for (int st = 0; st < 6; ++st) {
      f16x8 uf = *(const f16x8*)(s_u16 + lr * 196 + st * 32 + oct * 8);
      f16x8 b0 = *(const f16x8*)(ihT + ((wv    ) * 16 + lr) * 192 + st * 32 + oct * 8);
      f16x8 b1 = *(const f16x8*)(ihT + ((wv + 4) * 16 + lr) * 192 + st * 32 + oct * 8);
      f16x8 b2 = *(const f16x8*)(ihT + ((wv + 8) * 16 + lr) * 192 + st * 32 + oct * 8);
      aX0 = MFH(uf, b0, aX0);
      aX1 = MFH(uf, b1, aX1);
      aX2 = MFH(uf, b2, aX2);
    }
    #pragma unroll
    for (int st = 0; st < 2; ++st) {
      f16x8 hf = *(const f16x8*)(s_hid16 + lr * 68 + st * 32 + oct * 8);
      f16x8 b0 = *(const f16x8*)(hhT + ((wv    ) * 16 + lr) * 64 + st * 32 + oct * 8);
      f16x8 b1 = *(const f16x8*)(hhT + ((wv + 4) * 16 + lr) * 64 + st * 32 + oct * 8);
      f16x8 b2 = *(const f16x8*)(hhT + ((wv + 8) * 16 + lr) * 64 + st * 32 + oct * 8);
      aX0 = MFH(hf, b0, aX0);
      aX1 = MFH(hf, b1, aX1);
      aH2 = MFH(hf, b2, aH2);
    }
    const int c0 = wv * 16 + lr;
    float bb0 = gbS[c0], bb1 = gbS[c0 + 64], bb2 = gbS[c0 + 128], bbh = gbH[c0];
    #pragma unroll
    for (int j = 0; j < 4; ++j) {
      int row = oct * 4 + j;
      float xr = aX0[j] + bb0;
      float xz = aX1[j] + bb1;
      float xn = aX2[j] + bb2;
      float hn = aH2[j] + bbh;
      float r  = __builtin_amdgcn_rcpf(1.f + __builtin_exp2f(-xr * LOG2E));
      float zg = __builtin_amdgcn_rcpf(1.f + __builtin_exp2f(-xz * LOG2E));
      float ta = xn + r * hn;
      float nc = 1.f - 2.f * __builtin_amdgcn_rcpf(1.f + __builtin_exp2f(2.f * LOG2E * ta));
      float hv = (float)s_hid16[row * 68 + c0];
      s_z16[row * 68 + c0] = (_Float16)((1.f - zg) * nc + zg * hv);
    }
  }
  __syncthreads();

  // ---------------- phase 5: fused head GEMM (waves 0,1) -------------------
  {
    const _Float16* bhT = (const _Float16*)((const char*)ws + OFF_BHD);
    if (wv < 2) {
      f16x8 a0 = *(const f16x8*)(s_z16 + lr * 68 + oct * 8);
      f16x8 a1 = *(const f16x8*)(s_z16 + lr * 68 + 32 + oct * 8);
      f16x8 b0 = *(const f16x8*)(bhT + (wv * 16 + lr) * 64 + oct * 8);
      f16x8 b1 = *(const f16x8*)(bhT + (wv * 16 + lr) * 64 + 32 + oct * 8);
      f32x4 td = ZERO4;
      td = MFH(a0, b0, td);
      td = MFH(a1, b1, td);
      const int col = wv * 16 + lr;
      #pragma unroll
      for (int j = 0; j < 4; ++j) {
        int row = oct * 4 + j;
        if (col < 25)      s_t16[row * 26 + col] = (_Float16)td[j];
        else if (col < 31) s_q[row * 22 + (col - 25)] = td[j] + bm[col - 25];
      }
    }
  }
  __syncthreads();
  // shoot logits: enemy raw from global (L2/L3) + t
  {
    const float* er = enemy_raw + (size_t)(bs0 + s) * 384 + ln * 24;
    const _Float16* tp = s_t16 + s * 26;
    float acc2 = (float)tp[24];
    #pragma unroll
    for (int k4 = 0; k4 < 6; ++k4) {
      float4 r4 = *(const float4*)(er + k4 * 4);
      acc2 += r4.x * (float)tp[k4*4]   + r4.y * (float)tp[k4*4+1]
            + r4.z * (float)tp[k4*4+2] + r4.w * (float)tp[k4*4+3];
    }
    s_q[s * 22 + 6 + ln] = acc2;
  }
  __syncthreads();
  // coalesced output tail
  for (int i = tid; i < 352; i += 256)
    out[(size_t)bs0 * 22 + i] = s_q[i];
  for (int i = tid; i < 1024; i += 256)
    out[(size_t)BN * 22 + (size_t)bs0 * 64 + i] = (float)s_z16[(i >> 6) * 68 + (i & 63)];
}

// ============================================================= launch =======
extern "C" void kernel_launch(void* const* d_in, const int* in_sizes, int n_in,
                              void* d_out, int out_size, void* d_ws, size_t ws_size,
                              hipStream_t stream) {
  (void)n_in; (void)out_size; (void)ws_size;
  const float* own_raw   = (const float*)d_in[0];
  const float* ally_raw  = (const float*)d_in[1];
  const float* enemy_raw = (const float*)d_in[2];
  const float* hidden    = (const float*)d_in[3];
  const float* hyp_W1    = (const float*)d_in[4];
  const float* hyp_b1    = (const float*)d_in[5];
  const float* hyp_W2    = (const float*)d_in[6];
  const float* hyp_b2    = (const float*)d_in[7];
  const float* Wa        = (const float*)d_in[8];
  const float* ba        = (const float*)d_in[9];
  const float* We        = (const float*)d_in[10];
  const float* be        = (const float*)d_in[11];
  const float* aWq       = (const float*)d_in[12];
  const float* aWk       = (const float*)d_in[13];
  const float* aWv       = (const float*)d_in[14];
  const float* aWo       = (const float*)d_in[15];
  const float* eWq       = (const float*)d_in[16];
  const float* eWk       = (const float*)d_in[17];
  const float* eWv       = (const float*)d_in[18];
  const float* eWo       = (const float*)d_in[19];
  const float* gWih      = (const float*)d_in[20];
  const float* gWhh      = (const float*)d_in[21];
  const float* gbih      = (const float*)d_in[22];
  const float* gbhh      = (const float*)d_in[23];
  const float* Wm        = (const float*)d_in[24];
  const float* bm        = (const float*)d_in[25];
  const float* WzK       = (const float*)d_in[26];
  const float* WEK       = (const float*)d_in[27];
  int BN = in_sizes[0] / 40;
  int blocks = BN / TB;

  hipLaunchKernelGGL(prep_kernel, dim3(53), dim3(256), 0, stream,
                     hyp_W1, hyp_b1, hyp_W2, hyp_b2, Wa, ba, We, be,
                     aWq, aWk, aWv, aWo, eWq, eWk, eWv, eWo,
                     gWih, gWhh, gbih, gbhh, WzK, WEK, Wm, d_ws);
  hipLaunchKernelGGL(agent_kernel, dim3(blocks), dim3(256), 0, stream,
                     own_raw, ally_raw, enemy_raw, hidden, bm,
                     d_ws, (float*)d_out, BN);
}

// Round 12
// 163.910 us; speedup vs baseline: 1.3486x; 1.1917x over previous
//
#include <hip/hip_runtime.h>
#include <hip/hip_bf16.h>
#include <math.h>

#define TB 32
#define LOG2E 1.44269504f

typedef float f32x4 __attribute__((ext_vector_type(4)));
typedef _Float16 f16x8 __attribute__((ext_vector_type(8)));
typedef _Float16 f16x4 __attribute__((ext_vector_type(4)));
typedef _Float16 f16x2 __attribute__((ext_vector_type(2)));

// ---------------- ws layout (bytes), all weight mats f16 [col][k] -----------
#define OFF_W1T  344064
#define OFF_WOA  352256   // [64][64] = aWo^T
#define OFF_WOE  360448   // [64][64] = eWo^T
#define OFF_VBA  368640   // [64h][32k] = We@Wv fused (k=24 bias row)
#define OFF_VBE  372736
#define OFF_GA   376832   // [128][64]
#define OFF_GE   393216
#define OFF_GIH  409600
#define OFF_GHH  483328
#define OFF_GBS  507904
#define OFF_GBH  508672
#define OFF_BHD  508928

#define MFH(a, b, c) __builtin_amdgcn_mfma_f32_16x16x32_f16((a), (b), (c), 0, 0, 0)

__device__ inline float dot2(f16x2 a, f16x2 b, float c) {
#if __has_builtin(__builtin_amdgcn_fdot2)
  return __builtin_amdgcn_fdot2(a, b, c, false);
#else
  return c + (float)a[0] * (float)b[0] + (float)a[1] * (float)b[1];
#endif
}

// ============================================================= prep =========
__global__ __launch_bounds__(256)
void prep_kernel(const float* __restrict__ hyp_W1, const float* __restrict__ hyp_b1,
                 const float* __restrict__ hyp_W2, const float* __restrict__ hyp_b2,
                 const float* __restrict__ Wa, const float* __restrict__ ba,
                 const float* __restrict__ We, const float* __restrict__ be,
                 const float* __restrict__ aWq, const float* __restrict__ aWk,
                 const float* __restrict__ aWv, const float* __restrict__ aWo,
                 const float* __restrict__ eWq, const float* __restrict__ eWk,
                 const float* __restrict__ eWv, const float* __restrict__ eWo,
                 const float* __restrict__ gWih, const float* __restrict__ gWhh,
                 const float* __restrict__ gbih, const float* __restrict__ gbhh,
                 const float* __restrict__ WzK, const float* __restrict__ WEK,
                 const float* __restrict__ Wm,
                 void* __restrict__ ws)
{
  const int b = blockIdx.x, t = threadIdx.x;
  if (b < 42) {
    _Float16* o = (_Float16*)ws;
    for (int i = t; i < 4096; i += 256) {
      int h = i >> 6, k = i & 63;
      float v;
      if (b < 40)       v = hyp_W2[(size_t)k * 2628 + b * 64 + h];
      else if (b == 40) v = hyp_W2[(size_t)k * 2628 + 2560 + h];
      else              v = (k < 40) ? hyp_b2[k * 64 + h]
                             : (k == 40 ? hyp_b2[2560 + h] : 0.0f);
      o[b * 4096 + i] = (_Float16)v;
    }
  } else if (b == 42) {
    _Float16* o = (_Float16*)((char*)ws + OFF_W1T);
    for (int i = t; i < 4096; i += 256) {
      int h = i >> 6, k = i & 63;
      float v = (k < 40) ? hyp_W1[k * 64 + h] : (k == 40 ? hyp_b1[h] : 0.0f);
      o[i] = (_Float16)v;
    }
  } else if (b == 43 || b == 44) {
    const float* M = (b == 43) ? aWo : eWo;
    _Float16* o = (_Float16*)((char*)ws + (b == 43 ? OFF_WOA : OFF_WOE));
    for (int i = t; i < 4096; i += 256)
      o[i] = (_Float16)M[(i & 63) * 64 + (i >> 6)];
  } else if (b == 45 || b == 46) {
    const float* Wemb = (b == 45) ? Wa : We;
    const float* bemb = (b == 45) ? ba : be;
    const float* Wv   = (b == 45) ? aWv : eWv;
    _Float16* o = (_Float16*)((char*)ws + (b == 45 ? OFF_VBA : OFF_VBE));
    for (int i = t; i < 2048; i += 256) {
      int h = i >> 5, k = i & 31;
      float v = 0.f;
      if (k < 24)       { for (int d = 0; d < 64; ++d) v += Wemb[k * 64 + d] * Wv[d * 64 + h]; }
      else if (k == 24) { for (int d = 0; d < 64; ++d) v += bemb[d] * Wv[d * 64 + h]; }
      o[i] = (_Float16)v;
    }
  } else if (b == 47 || b == 48) {
    const float* Wemb = (b == 47) ? Wa : We;
    const float* bemb = (b == 47) ? ba : be;
    const float* Wk   = (b == 47) ? aWk : eWk;
    const float* Wq   = (b == 47) ? aWq : eWq;
    _Float16* o = (_Float16*)((char*)ws + (b == 47 ? OFF_GA : OFF_GE));
    __shared__ float sKb[25 * 64];
    for (int i = t; i < 1600; i += 256) {
      int k = i >> 6, c = i & 63;
      float v = 0.f;
      if (k < 24)  { for (int d = 0; d < 64; ++d) v += Wemb[k * 64 + d] * Wk[d * 64 + c]; }
      else         { for (int d = 0; d < 64; ++d) v += bemb[d] * Wk[d * 64 + c]; }
      sKb[i] = v;
    }
    __syncthreads();
    for (int i = t; i < 8192; i += 256) {
      int col = i >> 6, d = i & 63;
      int h = col >> 5, kk = col & 31;
      float v = 0.f;
      if (kk < 25)
        for (int dh = 0; dh < 16; ++dh)
          v += Wq[d * 64 + h * 16 + dh] * sKb[kk * 64 + h * 16 + dh];
      o[i] = (_Float16)(v * 0.25f * LOG2E);
    }
  } else if (b == 49) {
    _Float16* o = (_Float16*)((char*)ws + OFF_GIH);
    for (int i = t; i < 36864; i += 256) {
      int d = i / 192, c = i - d * 192;
      o[c * 192 + d] = (_Float16)gWih[i];
    }
  } else if (b == 50) {
    _Float16* o = (_Float16*)((char*)ws + OFF_GHH);
    for (int i = t; i < 12288; i += 256) {
      int d = i / 192, c = i - d * 192;
      o[c * 64 + d] = (_Float16)gWhh[i];
    }
  } else if (b == 51) {
    float* gbS = (float*)((char*)ws + OFF_GBS);
    float* gbH = (float*)((char*)ws + OFF_GBH);
    if (t < 192) gbS[t] = gbih[t] + (t < 128 ? gbhh[t] : 0.0f);
    if (t < 64)  gbH[t] = gbhh[128 + t];
  } else if (b == 52) { // head B-matrix
    __shared__ float sWsK[24 * 64];
    __shared__ float sbw[64];
    _Float16* o = (_Float16*)((char*)ws + OFF_BHD);
    for (int i = t; i < 1536; i += 256) {
      int j = i >> 6, h = i & 63;
      float v = 0.f;
      for (int c = 0; c < 64; ++c) v += We[j * 64 + c] * WEK[c * 64 + h];
      sWsK[i] = v;
    }
    if (t < 64) {
      float v = 0.f;
      for (int c = 0; c < 64; ++c) v += be[c] * WEK[c * 64 + t];
      sbw[t] = v;
    }
    __syncthreads();
    for (int i = t; i < 2048; i += 256) {
      int col = i >> 6, c = i & 63;
      float v = 0.f;
      if (col < 24)       { for (int d = 0; d < 64; ++d) v += WzK[c * 64 + d] * sWsK[col * 64 + d]; }
      else if (col == 24) { for (int d = 0; d < 64; ++d) v += WzK[c * 64 + d] * sbw[d]; }
      else if (col < 31)  v = Wm[c * 6 + (col - 25)];
      o[i] = (_Float16)v;
    }
  }
}

// ============================================================= main =========
__global__ __launch_bounds__(256, 4)
void agent_kernel(
    const float* __restrict__ own_raw, const float* __restrict__ ally_raw,
    const float* __restrict__ enemy_raw, const float* __restrict__ hidden,
    const float* __restrict__ bm,
    const void* __restrict__ ws,
    float* __restrict__ out, int BN)
{
  // LDS = 12544 (u16) + 4352 (hid16) + 12544 (R2 union) = 29440 B
  __shared__ __align__(16) char s_all[29440];
  _Float16* s_u16   = (_Float16*)s_all;             // [32][196]
  _Float16* s_hid16 = (_Float16*)(s_all + 12544);   // [32][68]
  char*     sR2     = s_all + 16896;
  // ph0-2
  _Float16* s_own16 = (_Float16*)sR2;               // [32][52]
  _Float16* s_ownT  = (_Float16*)(sR2 + 3328);      // [40][32]
  _Float16* s_h116  = (_Float16*)(sR2 + 5888);      // [32][68]
  // ph3
  _Float16* s_w16   = (_Float16*)sR2;               // [32][130]
  _Float16* s_att16 = (_Float16*)sR2;               // [32][68] (post-score, w16 dead)
  _Float16* s_p16   = (_Float16*)(sR2 + 8320);      // [16][132]
  // ph4+
  _Float16* s_z16   = (_Float16*)sR2;               // [32][68]
  _Float16* s_t16   = (_Float16*)(sR2 + 4352);      // [32][26]
  float*    s_q     = (float*)(sR2 + 6016);         // [32][22]

  const int tid = threadIdx.x;
  const int bs0 = blockIdx.x * TB;
  const int l   = tid & 63;
  const int wv  = tid >> 6;
  const int lr  = l & 15;
  const int oct = l >> 4;
  const int s8  = tid >> 3;       // 0..31 (score/shoot sample)
  const int sh  = tid & 7;

  const f16x8 ZERO8F = {0,0,0,0,0,0,0,0};
  f16x8 ONE8F = ZERO8F; ONE8F[0] = (_Float16)1.0f;
  const f32x4 ZERO4 = {0.f, 0.f, 0.f, 0.f};

  // ---------------- phase 0: stage own (f16 + f16-T) + hidden --------------
  for (int i = tid; i < 640; i += 256) {
    int ss = i / 20, c = i - ss * 20;
    float2 v = *(const float2*)(own_raw + (size_t)(bs0 + ss) * 40 + c * 2);
    f16x2 pk; pk[0] = (_Float16)v.x; pk[1] = (_Float16)v.y;
    *(f16x2*)(s_own16 + ss * 52 + c * 2) = pk;
  }
  for (int i = tid; i < 1280; i += 256) {      // ownT[f][s] f16
    int f = i >> 5, s2 = i & 31;
    s_ownT[i] = (_Float16)own_raw[(size_t)(bs0 + s2) * 40 + f];
  }
  for (int i = tid; i < 1024; i += 256) {
    int ss = i >> 5, c = i & 31;
    float2 v = *(const float2*)(hidden + (size_t)(bs0 + ss) * 64 + c * 2);
    f16x2 pk; pk[0] = (_Float16)v.x; pk[1] = (_Float16)v.y;
    *(f16x2*)(s_hid16 + ss * 68 + c * 2) = pk;
  }
  __syncthreads();

  // ---------------- phase 1: h1 = relu(own @ W1 + b1), 2 row-tiles ---------
  {
    const _Float16* w1t = (const _Float16*)((const char*)ws + OFF_W1T);
    f16x8 b0 = *(const f16x8*)(w1t + (wv * 16 + lr) * 64 + oct * 8);
    f16x8 b1 = *(const f16x8*)(w1t + (wv * 16 + lr) * 64 + 32 + oct * 8);
    #pragma unroll
    for (int rt = 0; rt < 2; ++rt) {
      f16x8 a0 = *(const f16x8*)(s_own16 + (rt * 16 + lr) * 52 + oct * 8);
      f16x8 a1;
      if (oct == 0)      a1 = *(const f16x8*)(s_own16 + (rt * 16 + lr) * 52 + 32);
      else if (oct == 1) a1 = ONE8F;
      else               a1 = ZERO8F;
      f32x4 acc = ZERO4;
      acc = MFH(a0, b0, acc);
      acc = MFH(a1, b1, acc);
      #pragma unroll
      for (int j = 0; j < 4; ++j)
        s_h116[(rt * 16 + oct * 4 + j) * 68 + wv * 16 + lr] = (_Float16)fmaxf(acc[j], 0.f);
    }
  }
  __syncthreads();

  // ---------------- phase 2: own_e, scale-in-acc, 2 row-tiles, shared B ----
  {
    const _Float16* bb = (const _Float16*)ws + (size_t)(wv * 16 + lr) * 64 + oct * 8;
    f16x8 h0f0 = *(const f16x8*)(s_h116 + lr * 68 + oct * 8);
    f16x8 h1f0 = *(const f16x8*)(s_h116 + lr * 68 + 32 + oct * 8);
    f16x8 h0f1 = *(const f16x8*)(s_h116 + (16 + lr) * 68 + oct * 8);
    f16x8 h1f1 = *(const f16x8*)(s_h116 + (16 + lr) * 68 + 32 + oct * 8);
    f32x4 acc0 = ZERO4, acc1 = ZERO4;
    #pragma unroll 4
    for (int f = 0; f < 40; ++f) {
      f16x8 b0 = *(const f16x8*)(bb + (size_t)f * 4096);
      f16x8 b1 = *(const f16x8*)(bb + (size_t)f * 4096 + 32);
      f32x4 y0 = MFH(h0f0, b0, ZERO4); y0 = MFH(h1f0, b1, y0);
      f32x4 y1 = MFH(h0f1, b0, ZERO4); y1 = MFH(h1f1, b1, y1);
      f16x4 ov0 = *(const f16x4*)(s_ownT + f * 32 + oct * 4);
      f16x4 ov1 = *(const f16x4*)(s_ownT + f * 32 + 16 + oct * 4);
      #pragma unroll
      for (int j = 0; j < 4; ++j) {
        acc0[j] += (float)ov0[j] * y0[j];
        acc1[j] += (float)ov1[j] * y1[j];
      }
    }
    f32x4 aD0 = ZERO4, aD1 = ZERO4;
    {
      f16x8 b0 = *(const f16x8*)(bb + (size_t)40 * 4096);
      f16x8 b1 = *(const f16x8*)(bb + (size_t)40 * 4096 + 32);
      aD0 = MFH(h0f0, b0, aD0); aD0 = MFH(h1f0, b1, aD0);
      aD1 = MFH(h0f1, b0, aD1); aD1 = MFH(h1f1, b1, aD1);
    }
    {
      f16x8 b0 = *(const f16x8*)(bb + (size_t)41 * 4096);
      f16x8 b1 = *(const f16x8*)(bb + (size_t)41 * 4096 + 32);
      #pragma unroll
      for (int rt = 0; rt < 2; ++rt) {
        f16x8 a0 = *(const f16x8*)(s_own16 + (rt * 16 + lr) * 52 + oct * 8);
        f16x8 a1;
        if (oct == 0)      a1 = *(const f16x8*)(s_own16 + (rt * 16 + lr) * 52 + 32);
        else if (oct == 1) a1 = ONE8F;
        else               a1 = ZERO8F;
        if (rt) { aD1 = MFH(a0, b0, aD1); aD1 = MFH(a1, b1, aD1); }
        else    { aD0 = MFH(a0, b0, aD0); aD0 = MFH(a1, b1, aD0); }
      }
    }
    #pragma unroll
    for (int j = 0; j < 4; ++j) {
      s_u16[(oct * 4 + j) * 196 + wv * 16 + lr]        = (_Float16)(acc0[j] + aD0[j]);
      s_u16[(16 + oct * 4 + j) * 196 + wv * 16 + lr]   = (_Float16)(acc1[j] + aD1[j]);
    }
  }
  __syncthreads();

  // ---------------- phase 3: MHA (G-trick, raw from global) ----------------
  for (int side = 0; side < 2; ++side) {
    const int n_ent = side ? 16 : 15;
    const int rstr  = side ? 384 : 360;
    const float* rawg = side ? enemy_raw : ally_raw;
    const _Float16* woT = (const _Float16*)((const char*)ws + (side ? OFF_WOE : OFF_WOA));
    const _Float16* vbT = (const _Float16*)((const char*)ws + (side ? OFF_VBE : OFF_VBA));
    const _Float16* gT  = (const _Float16*)((const char*)ws + (side ? OFF_GE  : OFF_GA));

    // --- w = own_e @ G -> w16 (2 row-tiles, shared B) ---
    {
      f16x8 a00 = *(const f16x8*)(s_u16 + lr * 196 + oct * 8);
      f16x8 a10 = *(const f16x8*)(s_u16 + lr * 196 + 32 + oct * 8);
      f16x8 a01 = *(const f16x8*)(s_u16 + (16 + lr) * 196 + oct * 8);
      f16x8 a11 = *(const f16x8*)(s_u16 + (16 + lr) * 196 + 32 + oct * 8);
      #pragma unroll
      for (int t2 = 0; t2 < 2; ++t2) {
        int col = wv * 32 + t2 * 16 + lr;
        f16x8 b0 = *(const f16x8*)(gT + col * 64 + oct * 8);
        f16x8 b1 = *(const f16x8*)(gT + col * 64 + 32 + oct * 8);
        f32x4 ac0 = ZERO4, ac1 = ZERO4;
        ac0 = MFH(a00, b0, ac0); ac0 = MFH(a10, b1, ac0);
        ac1 = MFH(a01, b0, ac1); ac1 = MFH(a11, b1, ac1);
        #pragma unroll
        for (int j = 0; j < 4; ++j) {
          s_w16[(oct * 4 + j) * 130 + col]      = (_Float16)ac0[j];
          s_w16[(16 + oct * 4 + j) * 130 + col] = (_Float16)ac1[j];
        }
      }
    }
    __syncthreads();

    // --- score: thread (s8, entities sh & sh+8); 8-lane softmax ---
    {
      float sc[2][4];
      #pragma unroll
      for (int e = 0; e < 2; ++e) {
        sc[e][0] = sc[e][1] = sc[e][2] = sc[e][3] = -2.0e9f;
        int n = sh + e * 8;
        if (n < n_ent) {
          const float* rp = rawg + (size_t)(bs0 + s8) * rstr + n * 24;
          float r[24];
          #pragma unroll
          for (int k4 = 0; k4 < 6; ++k4)
            *(float4*)(r + k4 * 4) = *(const float4*)(rp + k4 * 4);
          unsigned orv = 0u;
          #pragma unroll
          for (int k = 0; k < 24; ++k) orv |= (r[k] != 0.0f) ? 1u : 0u;
          f16x2 rh[12];
          #pragma unroll
          for (int p = 0; p < 12; ++p) {
            rh[p][0] = (_Float16)r[2 * p];
            rh[p][1] = (_Float16)r[2 * p + 1];
          }
          const _Float16* wp = s_w16 + s8 * 130;
          #pragma unroll
          for (int h = 0; h < 4; ++h) {
            float a = (float)wp[h * 32 + 24];
            #pragma unroll
            for (int p = 0; p < 12; ++p)
              a = dot2(rh[p], *(const f16x2*)(wp + h * 32 + 2 * p), a);
            sc[e][h] = orv ? a : -1.0e9f;
          }
        }
      }
      float m[4], lsum[4];
      #pragma unroll
      for (int h = 0; h < 4; ++h) m[h] = fmaxf(sc[0][h], sc[1][h]);
      #pragma unroll
      for (int d = 1; d < 8; d <<= 1) {
        #pragma unroll
        for (int h = 0; h < 4; ++h) m[h] = fmaxf(m[h], __shfl_xor(m[h], d));
      }
      float p0[4], p1[4];
      #pragma unroll
      for (int h = 0; h < 4; ++h) {
        p0[h] = __builtin_exp2f(sc[0][h] - m[h]);
        p1[h] = __builtin_exp2f(sc[1][h] - m[h]);
        lsum[h] = p0[h] + p1[h];
      }
      #pragma unroll
      for (int d = 1; d < 8; d <<= 1) {
        #pragma unroll
        for (int h = 0; h < 4; ++h) lsum[h] += __shfl_xor(lsum[h], d);
      }
      float rl[4];
      #pragma unroll
      for (int h = 0; h < 4; ++h) rl[h] = __builtin_amdgcn_rcpf(lsum[h]);
      {
        f16x4 pk;
        #pragma unroll
        for (int h = 0; h < 4; ++h) pk[h] = (_Float16)(p0[h] * rl[h]);
        *(f16x4*)(s_p16 + sh * 132 + s8 * 4) = pk;
      }
      if (sh + 8 < n_ent) {
        f16x4 pk;
        #pragma unroll
        for (int h = 0; h < 4; ++h) pk[h] = (_Float16)(p1[h] * rl[h]);
        *(f16x4*)(s_p16 + (sh + 8) * 132 + s8 * 4) = pk;
      }
    }
    __syncthreads();

    // --- PV: raw re-read from global (L2-hot), 2 row-tiles ---
    {
      f16x8 vbF = *(const f16x8*)(vbT + (wv * 16 + lr) * 32 + oct * 8);
      const float* rpv0 = rawg + (size_t)(bs0 + lr) * rstr + oct * 8;
      const float* rpv1 = rawg + (size_t)(bs0 + 16 + lr) * rstr + oct * 8;
      f32x4 oac0 = ZERO4, oac1 = ZERO4;
      #pragma unroll
      for (int i = 0; i < 16; ++i) {
        if (i >= n_ent) break;
        _Float16 pw0 = s_p16[i * 132 + lr * 4 + wv];
        _Float16 pw1 = s_p16[i * 132 + (16 + lr) * 4 + wv];
        f16x8 fr0, fr1;
        if (oct < 3) {
          float4 a = *(const float4*)(rpv0 + i * 24);
          float4 b = *(const float4*)(rpv0 + i * 24 + 4);
          fr0[0] = (_Float16)a.x * pw0; fr0[1] = (_Float16)a.y * pw0;
          fr0[2] = (_Float16)a.z * pw0; fr0[3] = (_Float16)a.w * pw0;
          fr0[4] = (_Float16)b.x * pw0; fr0[5] = (_Float16)b.y * pw0;
          fr0[6] = (_Float16)b.z * pw0; fr0[7] = (_Float16)b.w * pw0;
          float4 c = *(const float4*)(rpv1 + i * 24);
          float4 d = *(const float4*)(rpv1 + i * 24 + 4);
          fr1[0] = (_Float16)c.x * pw1; fr1[1] = (_Float16)c.y * pw1;
          fr1[2] = (_Float16)c.z * pw1; fr1[3] = (_Float16)c.w * pw1;
          fr1[4] = (_Float16)d.x * pw1; fr1[5] = (_Float16)d.y * pw1;
          fr1[6] = (_Float16)d.z * pw1; fr1[7] = (_Float16)d.w * pw1;
        } else {
          fr0 = ZERO8F; fr0[0] = pw0;
          fr1 = ZERO8F; fr1[0] = pw1;
        }
        oac0 = MFH(fr0, vbF, oac0);
        oac1 = MFH(fr1, vbF, oac1);
      }
      __syncthreads();   // w16 reads (score) fully done before att16 overwrite
      #pragma unroll
      for (int j = 0; j < 4; ++j) {
        s_att16[(oct * 4 + j) * 68 + wv * 16 + lr]      = (_Float16)oac0[j];
        s_att16[(16 + oct * 4 + j) * 68 + wv * 16 + lr] = (_Float16)oac1[j];
      }
    }
    __syncthreads();

    // --- o-GEMM -> u[:, 64+side*64] (2 row-tiles, shared B) ---
    {
      f16x8 b0 = *(const f16x8*)(woT + (wv * 16 + lr) * 64 + oct * 8);
      f16x8 b1 = *(const f16x8*)(woT + (wv * 16 + lr) * 64 + 32 + oct * 8);
      #pragma unroll
      for (int rt = 0; rt < 2; ++rt) {
        f16x8 a0 = *(const f16x8*)(s_att16 + (rt * 16 + lr) * 68 + oct * 8);
        f16x8 a1 = *(const f16x8*)(s_att16 + (rt * 16 + lr) * 68 + 32 + oct * 8);
        f32x4 oa = ZERO4;
        oa = MFH(a0, b0, oa);
        oa = MFH(a1, b1, oa);
        #pragma unroll
        for (int j = 0; j < 4; ++j)
          s_u16[(rt * 16 + oct * 4 + j) * 196 + 64 + side * 64 + wv * 16 + lr] = (_Float16)oa[j];
      }
    }
    __syncthreads();
  }

  // ---------------- phase 4: GRU (f16 MFMA, 2 row-tiles, shared B) ---------
  {
    const _Float16* ihT = (const _Float16*)((const char*)ws + OFF_GIH);
    const _Float16* hhT = (const _Float16*)((const char*)ws + OFF_GHH);
    const float* gbS = (const float*)((const char*)ws + OFF_GBS);
    const float* gbH = (const float*)((const char*)ws + OFF_GBH);
    f32x4 aX0[2] = {ZERO4, ZERO4}, aX1[2] = {ZERO4, ZERO4};
    f32x4 aX2[2] = {ZERO4, ZERO4}, aH2[2] = {ZERO4, ZERO4};
    #pragma unroll
    for (int st = 0; st < 6; ++st) {
      f16x8 uf0 = *(const f16x8*)(s_u16 + lr * 196 + st * 32 + oct * 8);
      f16x8 uf1 = *(const f16x8*)(s_u16 + (16 + lr) * 196 + st * 32 + oct * 8);
      f16x8 b0 = *(const f16x8*)(ihT + ((wv    ) * 16 + lr) * 192 + st * 32 + oct * 8);
      f16x8 b1 = *(const f16x8*)(ihT + ((wv + 4) * 16 + lr) * 192 + st * 32 + oct * 8);
      f16x8 b2 = *(const f16x8*)(ihT + ((wv + 8) * 16 + lr) * 192 + st * 32 + oct * 8);
      aX0[0] = MFH(uf0, b0, aX0[0]);  aX0[1] = MFH(uf1, b0, aX0[1]);
      aX1[0] = MFH(uf0, b1, aX1[0]);  aX1[1] = MFH(uf1, b1, aX1[1]);
      aX2[0] = MFH(uf0, b2, aX2[0]);  aX2[1] = MFH(uf1, b2, aX2[1]);
    }
    #pragma unroll
    for (int st = 0; st < 2; ++st) {
      f16x8 hf0 = *(const f16x8*)(s_hid16 + lr * 68 + st * 32 + oct * 8);
      f16x8 hf1 = *(const f16x8*)(s_hid16 + (16 + lr) * 68 + st * 32 + oct * 8);
      f16x8 b0 = *(const f16x8*)(hhT + ((wv    ) * 16 + lr) * 64 + st * 32 + oct * 8);
      f16x8 b1 = *(const f16x8*)(hhT + ((wv + 4) * 16 + lr) * 64 + st * 32 + oct * 8);
      f16x8 b2 = *(const f16x8*)(hhT + ((wv + 8) * 16 + lr) * 64 + st * 32 + oct * 8);
      aX0[0] = MFH(hf0, b0, aX0[0]);  aX0[1] = MFH(hf1, b0, aX0[1]);
      aX1[0] = MFH(hf0, b1, aX1[0]);  aX1[1] = MFH(hf1, b1, aX1[1]);
      aH2[0] = MFH(hf0, b2, aH2[0]);  aH2[1] = MFH(hf1, b2, aH2[1]);
    }
    const int c0 = wv * 16 + lr;
    float bb0 = gbS[c0], bb1 = gbS[c0 + 64], bb2 = gbS[c0 + 128], bbh = gbH[c0];
    __syncthreads();   // all s_u16 reads done before z16 overwrites R2
    #pragma unroll
    for (int rt = 0; rt < 2; ++rt) {
      #pragma unroll
      for (int j = 0; j < 4; ++j) {
        int row = rt * 16 + oct * 4 + j;
        float xr = aX0[rt][j] + bb0;
        float xz = aX1[rt][j] + bb1;
        float xn = aX2[rt][j] + bb2;
        float hn = aH2[rt][j] + bbh;
        float r  = __builtin_amdgcn_rcpf(1.f + __builtin_exp2f(-xr * LOG2E));
        float zg = __builtin_amdgcn_rcpf(1.f + __builtin_exp2f(-xz * LOG2E));
        float ta = xn + r * hn;
        float nc = 1.f - 2.f * __builtin_amdgcn_rcpf(1.f + __builtin_exp2f(2.f * LOG2E * ta));
        float hv = (float)s_hid16[row * 68 + c0];
        s_z16[row * 68 + c0] = (_Float16)((1.f - zg) * nc + zg * hv);
      }
    }
  }
  __syncthreads();

  // ---------------- phase 5: fused head GEMM (all 4 waves) -----------------
  {
    const _Float16* bhT = (const _Float16*)((const char*)ws + OFF_BHD);
    const int rt = wv >> 1;
    const int col = (wv & 1) * 16 + lr;
    f16x8 a0 = *(const f16x8*)(s_z16 + (rt * 16 + lr) * 68 + oct * 8);
    f16x8 a1 = *(const f16x8*)(s_z16 + (rt * 16 + lr) * 68 + 32 + oct * 8);
    f16x8 b0 = *(const f16x8*)(bhT + col * 64 + oct * 8);
    f16x8 b1 = *(const f16x8*)(bhT + col * 64 + 32 + oct * 8);
    f32x4 td = ZERO4;
    td = MFH(a0, b0, td);
    td = MFH(a1, b1, td);
    #pragma unroll
    for (int j = 0; j < 4; ++j) {
      int row = rt * 16 + oct * 4 + j;
      if (col < 25)      s_t16[row * 26 + col] = (_Float16)td[j];
      else if (col < 31) s_q[row * 22 + (col - 25)] = td[j] + bm[col - 25];
    }
  }
  __syncthreads();
  // shoot logits: thread (s8, entities sh & sh+8)
  {
    const _Float16* tp = s_t16 + s8 * 26;
    #pragma unroll
    for (int e = 0; e < 2; ++e) {
      int m = sh + e * 8;
      const float* er = enemy_raw + (size_t)(bs0 + s8) * 384 + m * 24;
      float acc2 = (float)tp[24];
      #pragma unroll
      for (int k4 = 0; k4 < 6; ++k4) {
        float4 r4 = *(const float4*)(er + k4 * 4);
        acc2 += r4.x * (float)tp[k4*4]   + r4.y * (float)tp[k4*4+1]
              + r4.z * (float)tp[k4*4+2] + r4.w * (float)tp[k4*4+3];
      }
      s_q[s8 * 22 + 6 + m] = acc2;
    }
  }
  __syncthreads();
  // coalesced output tail
  for (int i = tid; i < 704; i += 256)
    out[(size_t)bs0 * 22 + i] = s_q[i];
  for (int i = tid; i < 2048; i += 256)
    out[(size_t)BN * 22 + (size_t)bs0 * 64 + i] = (float)s_z16[(i >> 6) * 68 + (i & 63)];
}

// ============================================================= launch =======
extern "C" void kernel_launch(void* const* d_in, const int* in_sizes, int n_in,
                              void* d_out, int out_size, void* d_ws, size_t ws_size,
                              hipStream_t stream) {
  (void)n_in; (void)out_size; (void)ws_size;
  const float* own_raw   = (const float*)d_in[0];
  const float* ally_raw  = (const float*)d_in[1];
  const float* enemy_raw = (const float*)d_in[2];
  const float* hidden    = (const float*)d_in[3];
  const float* hyp_W1    = (const float*)d_in[4];
  const float* hyp_b1    = (const float*)d_in[5];
  const float* hyp_W2    = (const float*)d_in[6];
  const float* hyp_b2    = (const float*)d_in[7];
  const float* Wa        = (const float*)d_in[8];
  const float* ba        = (const float*)d_in[9];
  const float* We        = (const float*)d_in[10];
  const float* be        = (const float*)d_in[11];
  const float* aWq       = (const float*)d_in[12];
  const float* aWk       = (const float*)d_in[13];
  const float* aWv       = (const float*)d_in[14];
  const float* aWo       = (const float*)d_in[15];
  const float* eWq       = (const float*)d_in[16];
  const float* eWk       = (const float*)d_in[17];
  const float* eWv       = (const float*)d_in[18];
  const float* eWo       = (const float*)d_in[19];
  const float* gWih      = (const float*)d_in[20];
  const float* gWhh      = (const float*)d_in[21];
  const float* gbih      = (const float*)d_in[22];
  const float* gbhh      = (const float*)d_in[23];
  const float* Wm        = (const float*)d_in[24];
  const float* bm        = (const float*)d_in[25];
  const float* WzK       = (const float*)d_in[26];
  const float* WEK       = (const float*)d_in[27];
  int BN = in_sizes[0] / 40;
  int blocks = BN / TB;

  hipLaunchKernelGGL(prep_kernel, dim3(53), dim3(256), 0, stream,
                     hyp_W1, hyp_b1, hyp_W2, hyp_b2, Wa, ba, We, be,
                     aWq, aWk, aWv, aWo, eWq, eWk, eWv, eWo,
                     gWih, gWhh, gbih, gbhh, WzK, WEK, Wm, d_ws);
  hipLaunchKernelGGL(agent_kernel, dim3(blocks), dim3(256), 0, stream,
                     own_raw, ally_raw, enemy_raw, hidden, bm,
                     d_ws, (float*)d_out, BN);
}

// Round 13
// 157.068 us; speedup vs baseline: 1.4074x; 1.0436x over previous
//
#include <hip/hip_runtime.h>
#include <hip/hip_bf16.h>
#include <math.h>

#define TB 32
#define LOG2E 1.44269504f

typedef float f32x4 __attribute__((ext_vector_type(4)));
typedef _Float16 f16x8 __attribute__((ext_vector_type(8)));
typedef _Float16 f16x4 __attribute__((ext_vector_type(4)));
typedef _Float16 f16x2 __attribute__((ext_vector_type(2)));

// ---------------- ws layout (bytes), all weight mats f16 [col][k] -----------
#define OFF_W1T  344064
#define OFF_WOA  352256   // [64][64] = aWo^T
#define OFF_WOE  360448   // [64][64] = eWo^T
#define OFF_VBA  368640   // [64h][32k] = We@Wv fused (k=24 bias row)
#define OFF_VBE  372736
#define OFF_GA   376832   // [128][64]
#define OFF_GE   393216
#define OFF_GIH  409600
#define OFF_GHH  483328
#define OFF_GBS  507904
#define OFF_GBH  508672
#define OFF_BHD  508928

#define MFH(a, b, c) __builtin_amdgcn_mfma_f32_16x16x32_f16((a), (b), (c), 0, 0, 0)

__device__ inline float dot2(f16x2 a, f16x2 b, float c) {
#if __has_builtin(__builtin_amdgcn_fdot2)
  return __builtin_amdgcn_fdot2(a, b, c, false);
#else
  return c + (float)a[0] * (float)b[0] + (float)a[1] * (float)b[1];
#endif
}
__device__ inline f16x2 pk2(float x, float y) {
  f16x2 r; r[0] = (_Float16)x; r[1] = (_Float16)y; return r;
}

// ============================================================= prep =========
__global__ __launch_bounds__(256)
void prep_kernel(const float* __restrict__ hyp_W1, const float* __restrict__ hyp_b1,
                 const float* __restrict__ hyp_W2, const float* __restrict__ hyp_b2,
                 const float* __restrict__ Wa, const float* __restrict__ ba,
                 const float* __restrict__ We, const float* __restrict__ be,
                 const float* __restrict__ aWq, const float* __restrict__ aWk,
                 const float* __restrict__ aWv, const float* __restrict__ aWo,
                 const float* __restrict__ eWq, const float* __restrict__ eWk,
                 const float* __restrict__ eWv, const float* __restrict__ eWo,
                 const float* __restrict__ gWih, const float* __restrict__ gWhh,
                 const float* __restrict__ gbih, const float* __restrict__ gbhh,
                 const float* __restrict__ WzK, const float* __restrict__ WEK,
                 const float* __restrict__ Wm,
                 void* __restrict__ ws)
{
  const int b = blockIdx.x, t = threadIdx.x;
  if (b < 42) {
    _Float16* o = (_Float16*)ws;
    for (int i = t; i < 4096; i += 256) {
      int h = i >> 6, k = i & 63;
      float v;
      if (b < 40)       v = hyp_W2[(size_t)k * 2628 + b * 64 + h];
      else if (b == 40) v = hyp_W2[(size_t)k * 2628 + 2560 + h];
      else              v = (k < 40) ? hyp_b2[k * 64 + h]
                             : (k == 40 ? hyp_b2[2560 + h] : 0.0f);
      o[b * 4096 + i] = (_Float16)v;
    }
  } else if (b == 42) {
    _Float16* o = (_Float16*)((char*)ws + OFF_W1T);
    for (int i = t; i < 4096; i += 256) {
      int h = i >> 6, k = i & 63;
      float v = (k < 40) ? hyp_W1[k * 64 + h] : (k == 40 ? hyp_b1[h] : 0.0f);
      o[i] = (_Float16)v;
    }
  } else if (b == 43 || b == 44) {
    const float* M = (b == 43) ? aWo : eWo;
    _Float16* o = (_Float16*)((char*)ws + (b == 43 ? OFF_WOA : OFF_WOE));
    for (int i = t; i < 4096; i += 256)
      o[i] = (_Float16)M[(i & 63) * 64 + (i >> 6)];
  } else if (b == 45 || b == 46) {
    const float* Wemb = (b == 45) ? Wa : We;
    const float* bemb = (b == 45) ? ba : be;
    const float* Wv   = (b == 45) ? aWv : eWv;
    _Float16* o = (_Float16*)((char*)ws + (b == 45 ? OFF_VBA : OFF_VBE));
    for (int i = t; i < 2048; i += 256) {
      int h = i >> 5, k = i & 31;
      float v = 0.f;
      if (k < 24)       { for (int d = 0; d < 64; ++d) v += Wemb[k * 64 + d] * Wv[d * 64 + h]; }
      else if (k == 24) { for (int d = 0; d < 64; ++d) v += bemb[d] * Wv[d * 64 + h]; }
      o[i] = (_Float16)v;
    }
  } else if (b == 47 || b == 48) {
    const float* Wemb = (b == 47) ? Wa : We;
    const float* bemb = (b == 47) ? ba : be;
    const float* Wk   = (b == 47) ? aWk : eWk;
    const float* Wq   = (b == 47) ? aWq : eWq;
    _Float16* o = (_Float16*)((char*)ws + (b == 47 ? OFF_GA : OFF_GE));
    __shared__ float sKb[25 * 64];
    for (int i = t; i < 1600; i += 256) {
      int k = i >> 6, c = i & 63;
      float v = 0.f;
      if (k < 24)  { for (int d = 0; d < 64; ++d) v += Wemb[k * 64 + d] * Wk[d * 64 + c]; }
      else         { for (int d = 0; d < 64; ++d) v += bemb[d] * Wk[d * 64 + c]; }
      sKb[i] = v;
    }
    __syncthreads();
    for (int i = t; i < 8192; i += 256) {
      int col = i >> 6, d = i & 63;
      int h = col >> 5, kk = col & 31;
      float v = 0.f;
      if (kk < 25)
        for (int dh = 0; dh < 16; ++dh)
          v += Wq[d * 64 + h * 16 + dh] * sKb[kk * 64 + h * 16 + dh];
      o[i] = (_Float16)(v * 0.25f * LOG2E);
    }
  } else if (b == 49) {
    _Float16* o = (_Float16*)((char*)ws + OFF_GIH);
    for (int i = t; i < 36864; i += 256) {
      int d = i / 192, c = i - d * 192;
      o[c * 192 + d] = (_Float16)gWih[i];
    }
  } else if (b == 50) {
    _Float16* o = (_Float16*)((char*)ws + OFF_GHH);
    for (int i = t; i < 12288; i += 256) {
      int d = i / 192, c = i - d * 192;
      o[c * 64 + d] = (_Float16)gWhh[i];
    }
  } else if (b == 51) {
    float* gbS = (float*)((char*)ws + OFF_GBS);
    float* gbH = (float*)((char*)ws + OFF_GBH);
    if (t < 192) gbS[t] = gbih[t] + (t < 128 ? gbhh[t] : 0.0f);
    if (t < 64)  gbH[t] = gbhh[128 + t];
  } else if (b == 52) { // head B-matrix
    __shared__ float sWsK[24 * 64];
    __shared__ float sbw[64];
    _Float16* o = (_Float16*)((char*)ws + OFF_BHD);
    for (int i = t; i < 1536; i += 256) {
      int j = i >> 6, h = i & 63;
      float v = 0.f;
      for (int c = 0; c < 64; ++c) v += We[j * 64 + c] * WEK[c * 64 + h];
      sWsK[i] = v;
    }
    if (t < 64) {
      float v = 0.f;
      for (int c = 0; c < 64; ++c) v += be[c] * WEK[c * 64 + t];
      sbw[t] = v;
    }
    __syncthreads();
    for (int i = t; i < 2048; i += 256) {
      int col = i >> 6, c = i & 63;
      float v = 0.f;
      if (col < 24)       { for (int d = 0; d < 64; ++d) v += WzK[c * 64 + d] * sWsK[col * 64 + d]; }
      else if (col == 24) { for (int d = 0; d < 64; ++d) v += WzK[c * 64 + d] * sbw[d]; }
      else if (col < 31)  v = Wm[c * 6 + (col - 25)];
      o[i] = (_Float16)v;
    }
  }
}

// score helper: 6 float4 raw + w-row -> 4 head scores (masked), all in regs
#define SCORE_BODY(Q0,Q1,Q2,Q3,Q4,Q5,WP,SCV)                                  \
  {                                                                            \
    unsigned orv =                                                             \
      ((Q0.x!=0.f)|(Q0.y!=0.f)|(Q0.z!=0.f)|(Q0.w!=0.f)|                        \
       (Q1.x!=0.f)|(Q1.y!=0.f)|(Q1.z!=0.f)|(Q1.w!=0.f)|                        \
       (Q2.x!=0.f)|(Q2.y!=0.f)|(Q2.z!=0.f)|(Q2.w!=0.f)|                        \
       (Q3.x!=0.f)|(Q3.y!=0.f)|(Q3.z!=0.f)|(Q3.w!=0.f)|                        \
       (Q4.x!=0.f)|(Q4.y!=0.f)|(Q4.z!=0.f)|(Q4.w!=0.f)|                        \
       (Q5.x!=0.f)|(Q5.y!=0.f)|(Q5.z!=0.f)|(Q5.w!=0.f)) ? 1u : 0u;             \
    f16x2 r0 = pk2(Q0.x,Q0.y), r1 = pk2(Q0.z,Q0.w);                            \
    f16x2 r2 = pk2(Q1.x,Q1.y), r3 = pk2(Q1.z,Q1.w);                            \
    f16x2 r4 = pk2(Q2.x,Q2.y), r5 = pk2(Q2.z,Q2.w);                            \
    f16x2 r6 = pk2(Q3.x,Q3.y), r7 = pk2(Q3.z,Q3.w);                            \
    f16x2 r8 = pk2(Q4.x,Q4.y), r9 = pk2(Q4.z,Q4.w);                            \
    f16x2 r10 = pk2(Q5.x,Q5.y), r11 = pk2(Q5.z,Q5.w);                          \
    _Pragma("unroll")                                                          \
    for (int h = 0; h < 4; ++h) {                                              \
      const _Float16* wq = (WP) + h * 32;                                      \
      float a = (float)wq[24];                                                 \
      a = dot2(r0,  *(const f16x2*)(wq + 0),  a);                              \
      a = dot2(r1,  *(const f16x2*)(wq + 2),  a);                              \
      a = dot2(r2,  *(const f16x2*)(wq + 4),  a);                              \
      a = dot2(r3,  *(const f16x2*)(wq + 6),  a);                              \
      a = dot2(r4,  *(const f16x2*)(wq + 8),  a);                              \
      a = dot2(r5,  *(const f16x2*)(wq + 10), a);                              \
      a = dot2(r6,  *(const f16x2*)(wq + 12), a);                              \
      a = dot2(r7,  *(const f16x2*)(wq + 14), a);                              \
      a = dot2(r8,  *(const f16x2*)(wq + 16), a);                              \
      a = dot2(r9,  *(const f16x2*)(wq + 18), a);                              \
      a = dot2(r10, *(const f16x2*)(wq + 20), a);                              \
      a = dot2(r11, *(const f16x2*)(wq + 22), a);                              \
      SCV[h] = orv ? a : -1.0e9f;                                              \
    }                                                                          \
  }

// ============================================================= main =========
__global__ __launch_bounds__(256, 4)
void agent_kernel(
    const float* __restrict__ own_raw, const float* __restrict__ ally_raw,
    const float* __restrict__ enemy_raw, const float* __restrict__ hidden,
    const float* __restrict__ bm,
    const void* __restrict__ ws,
    float* __restrict__ out, int BN)
{
  // LDS = 12544 (u16) + 4352 (hid16) + 12544 (R2 union) = 29440 B
  __shared__ __align__(16) char s_all[29440];
  _Float16* s_u16   = (_Float16*)s_all;             // [32][196]
  _Float16* s_hid16 = (_Float16*)(s_all + 12544);   // [32][68]
  char*     sR2     = s_all + 16896;
  // ph0-2
  _Float16* s_own16 = (_Float16*)sR2;               // [32][52]
  _Float16* s_ownT  = (_Float16*)(sR2 + 3328);      // [40][32]
  _Float16* s_h116  = (_Float16*)(sR2 + 5888);      // [32][68]
  // ph3
  _Float16* s_w16   = (_Float16*)sR2;               // [32][130]
  _Float16* s_att16 = (_Float16*)sR2;               // [32][68] (post-score, w16 dead)
  _Float16* s_p16   = (_Float16*)(sR2 + 8320);      // [16][132]
  // ph4+
  _Float16* s_z16   = (_Float16*)sR2;               // [32][68]
  _Float16* s_t16   = (_Float16*)(sR2 + 4352);      // [32][26]
  float*    s_q     = (float*)(sR2 + 6016);         // [32][22]

  const int tid = threadIdx.x;
  const int bs0 = blockIdx.x * TB;
  const int l   = tid & 63;
  const int wv  = tid >> 6;
  const int lr  = l & 15;
  const int oct = l >> 4;
  const int s8  = tid >> 3;       // 0..31 (score/shoot sample)
  const int sh  = tid & 7;

  const f16x8 ZERO8F = {0,0,0,0,0,0,0,0};
  f16x8 ONE8F = ZERO8F; ONE8F[0] = (_Float16)1.0f;
  const f32x4 ZERO4 = {0.f, 0.f, 0.f, 0.f};

  // ---------------- phase 0: stage own (f16 + f16-T) + hidden --------------
  for (int i = tid; i < 640; i += 256) {
    int ss = i / 20, c = i - ss * 20;
    float2 v = *(const float2*)(own_raw + (size_t)(bs0 + ss) * 40 + c * 2);
    *(f16x2*)(s_own16 + ss * 52 + c * 2) = pk2(v.x, v.y);
  }
  for (int i = tid; i < 1280; i += 256) {      // ownT[f][s] f16
    int f = i >> 5, s2 = i & 31;
    s_ownT[i] = (_Float16)own_raw[(size_t)(bs0 + s2) * 40 + f];
  }
  for (int i = tid; i < 1024; i += 256) {
    int ss = i >> 5, c = i & 31;
    float2 v = *(const float2*)(hidden + (size_t)(bs0 + ss) * 64 + c * 2);
    *(f16x2*)(s_hid16 + ss * 68 + c * 2) = pk2(v.x, v.y);
  }
  __syncthreads();

  // ---------------- phase 1: h1 = relu(own @ W1 + b1), 2 row-tiles ---------
  {
    const _Float16* w1t = (const _Float16*)((const char*)ws + OFF_W1T);
    f16x8 b0 = *(const f16x8*)(w1t + (wv * 16 + lr) * 64 + oct * 8);
    f16x8 b1 = *(const f16x8*)(w1t + (wv * 16 + lr) * 64 + 32 + oct * 8);
    #pragma unroll
    for (int rt = 0; rt < 2; ++rt) {
      f16x8 a0 = *(const f16x8*)(s_own16 + (rt * 16 + lr) * 52 + oct * 8);
      f16x8 a1;
      if (oct == 0)      a1 = *(const f16x8*)(s_own16 + (rt * 16 + lr) * 52 + 32);
      else if (oct == 1) a1 = ONE8F;
      else               a1 = ZERO8F;
      f32x4 acc = ZERO4;
      acc = MFH(a0, b0, acc);
      acc = MFH(a1, b1, acc);
      #pragma unroll
      for (int j = 0; j < 4; ++j)
        s_h116[(rt * 16 + oct * 4 + j) * 68 + wv * 16 + lr] = (_Float16)fmaxf(acc[j], 0.f);
    }
  }
  __syncthreads();

  // ---------------- phase 2: own_e, scale-in-acc, 2 row-tiles, shared B ----
  {
    const _Float16* bb = (const _Float16*)ws + (size_t)(wv * 16 + lr) * 64 + oct * 8;
    f16x8 h0f0 = *(const f16x8*)(s_h116 + lr * 68 + oct * 8);
    f16x8 h1f0 = *(const f16x8*)(s_h116 + lr * 68 + 32 + oct * 8);
    f16x8 h0f1 = *(const f16x8*)(s_h116 + (16 + lr) * 68 + oct * 8);
    f16x8 h1f1 = *(const f16x8*)(s_h116 + (16 + lr) * 68 + 32 + oct * 8);
    f32x4 acc0 = ZERO4, acc1 = ZERO4;
    #pragma unroll 4
    for (int f = 0; f < 40; ++f) {
      f16x8 b0 = *(const f16x8*)(bb + (size_t)f * 4096);
      f16x8 b1 = *(const f16x8*)(bb + (size_t)f * 4096 + 32);
      f32x4 y0 = MFH(h0f0, b0, ZERO4); y0 = MFH(h1f0, b1, y0);
      f32x4 y1 = MFH(h0f1, b0, ZERO4); y1 = MFH(h1f1, b1, y1);
      f16x4 ov0 = *(const f16x4*)(s_ownT + f * 32 + oct * 4);
      f16x4 ov1 = *(const f16x4*)(s_ownT + f * 32 + 16 + oct * 4);
      #pragma unroll
      for (int j = 0; j < 4; ++j) {
        acc0[j] += (float)ov0[j] * y0[j];
        acc1[j] += (float)ov1[j] * y1[j];
      }
    }
    f32x4 aD0 = ZERO4, aD1 = ZERO4;
    {
      f16x8 b0 = *(const f16x8*)(bb + (size_t)40 * 4096);
      f16x8 b1 = *(const f16x8*)(bb + (size_t)40 * 4096 + 32);
      aD0 = MFH(h0f0, b0, aD0); aD0 = MFH(h1f0, b1, aD0);
      aD1 = MFH(h0f1, b0, aD1); aD1 = MFH(h1f1, b1, aD1);
    }
    {
      f16x8 b0 = *(const f16x8*)(bb + (size_t)41 * 4096);
      f16x8 b1 = *(const f16x8*)(bb + (size_t)41 * 4096 + 32);
      #pragma unroll
      for (int rt = 0; rt < 2; ++rt) {
        f16x8 a0 = *(const f16x8*)(s_own16 + (rt * 16 + lr) * 52 + oct * 8);
        f16x8 a1;
        if (oct == 0)      a1 = *(const f16x8*)(s_own16 + (rt * 16 + lr) * 52 + 32);
        else if (oct == 1) a1 = ONE8F;
        else               a1 = ZERO8F;
        if (rt) { aD1 = MFH(a0, b0, aD1); aD1 = MFH(a1, b1, aD1); }
        else    { aD0 = MFH(a0, b0, aD0); aD0 = MFH(a1, b1, aD0); }
      }
    }
    #pragma unroll
    for (int j = 0; j < 4; ++j) {
      s_u16[(oct * 4 + j) * 196 + wv * 16 + lr]        = (_Float16)(acc0[j] + aD0[j]);
      s_u16[(16 + oct * 4 + j) * 196 + wv * 16 + lr]   = (_Float16)(acc1[j] + aD1[j]);
    }
  }
  __syncthreads();

  // ---------------- phase 3: MHA (G-trick, raw from global, prefetch) ------
  for (int side = 0; side < 2; ++side) {
    const int n_ent = side ? 16 : 15;
    const int rstr  = side ? 384 : 360;
    const float* rawg = side ? enemy_raw : ally_raw;
    const _Float16* woT = (const _Float16*)((const char*)ws + (side ? OFF_WOE : OFF_WOA));
    const _Float16* vbT = (const _Float16*)((const char*)ws + (side ? OFF_VBE : OFF_VBA));
    const _Float16* gT  = (const _Float16*)((const char*)ws + (side ? OFF_GE  : OFF_GA));

    // --- w = own_e @ G -> w16 (2 row-tiles, shared B) ---
    {
      f16x8 a00 = *(const f16x8*)(s_u16 + lr * 196 + oct * 8);
      f16x8 a10 = *(const f16x8*)(s_u16 + lr * 196 + 32 + oct * 8);
      f16x8 a01 = *(const f16x8*)(s_u16 + (16 + lr) * 196 + oct * 8);
      f16x8 a11 = *(const f16x8*)(s_u16 + (16 + lr) * 196 + 32 + oct * 8);
      #pragma unroll
      for (int t2 = 0; t2 < 2; ++t2) {
        int col = wv * 32 + t2 * 16 + lr;
        f16x8 b0 = *(const f16x8*)(gT + col * 64 + oct * 8);
        f16x8 b1 = *(const f16x8*)(gT + col * 64 + 32 + oct * 8);
        f32x4 ac0 = ZERO4, ac1 = ZERO4;
        ac0 = MFH(a00, b0, ac0); ac0 = MFH(a10, b1, ac0);
        ac1 = MFH(a01, b0, ac1); ac1 = MFH(a11, b1, ac1);
        #pragma unroll
        for (int j = 0; j < 4; ++j) {
          s_w16[(oct * 4 + j) * 130 + col]      = (_Float16)ac0[j];
          s_w16[(16 + oct * 4 + j) * 130 + col] = (_Float16)ac1[j];
        }
      }
    }

    // --- prefetch score raw rows (issued BEFORE the w16 barrier) ---
    float4 qa0, qa1, qa2, qa3, qa4, qa5, qb0, qb1, qb2, qb3, qb4, qb5;
    {
      const int n1 = (sh + 8 < n_ent) ? (sh + 8) : (n_ent - 1);
      const float* rp0 = rawg + (size_t)(bs0 + s8) * rstr + sh * 24;
      const float* rp1 = rawg + (size_t)(bs0 + s8) * rstr + n1 * 24;
      qa0 = *(const float4*)(rp0);      qa1 = *(const float4*)(rp0 + 4);
      qa2 = *(const float4*)(rp0 + 8);  qa3 = *(const float4*)(rp0 + 12);
      qa4 = *(const float4*)(rp0 + 16); qa5 = *(const float4*)(rp0 + 20);
      qb0 = *(const float4*)(rp1);      qb1 = *(const float4*)(rp1 + 4);
      qb2 = *(const float4*)(rp1 + 8);  qb3 = *(const float4*)(rp1 + 12);
      qb4 = *(const float4*)(rp1 + 16); qb5 = *(const float4*)(rp1 + 20);
    }
    __syncthreads();

    // --- score: thread (s8, entities sh & sh+8); 8-lane softmax ---
    {
      const _Float16* wp = s_w16 + s8 * 130;
      f32x4 sc0, sc1;
      SCORE_BODY(qa0, qa1, qa2, qa3, qa4, qa5, wp, sc0);
      SCORE_BODY(qb0, qb1, qb2, qb3, qb4, qb5, wp, sc1);
      if (sh + 8 >= n_ent) {
        #pragma unroll
        for (int h = 0; h < 4; ++h) sc1[h] = -2.0e9f;
      }
      f32x4 m, lsum, p0v, p1v;
      #pragma unroll
      for (int h = 0; h < 4; ++h) m[h] = fmaxf(sc0[h], sc1[h]);
      #pragma unroll
      for (int d = 1; d < 8; d <<= 1) {
        #pragma unroll
        for (int h = 0; h < 4; ++h) m[h] = fmaxf(m[h], __shfl_xor(m[h], d));
      }
      #pragma unroll
      for (int h = 0; h < 4; ++h) {
        p0v[h] = __builtin_exp2f(sc0[h] - m[h]);
        p1v[h] = __builtin_exp2f(sc1[h] - m[h]);
        lsum[h] = p0v[h] + p1v[h];
      }
      #pragma unroll
      for (int d = 1; d < 8; d <<= 1) {
        #pragma unroll
        for (int h = 0; h < 4; ++h) lsum[h] += __shfl_xor(lsum[h], d);
      }
      f32x4 rl;
      #pragma unroll
      for (int h = 0; h < 4; ++h) rl[h] = __builtin_amdgcn_rcpf(lsum[h]);
      {
        f16x4 pk;
        #pragma unroll
        for (int h = 0; h < 4; ++h) pk[h] = (_Float16)(p0v[h] * rl[h]);
        *(f16x4*)(s_p16 + sh * 132 + s8 * 4) = pk;
      }
      if (sh + 8 < n_ent) {
        f16x4 pk;
        #pragma unroll
        for (int h = 0; h < 4; ++h) pk[h] = (_Float16)(p1v[h] * rl[h]);
        *(f16x4*)(s_p16 + (sh + 8) * 132 + s8 * 4) = pk;
      }
    }
    __syncthreads();

    // --- PV: raw re-read from global (L2-hot), 2 row-tiles ---
    {
      f16x8 vbF = *(const f16x8*)(vbT + (wv * 16 + lr) * 32 + oct * 8);
      const float* rpv0 = rawg + (size_t)(bs0 + lr) * rstr + oct * 8;
      const float* rpv1 = rawg + (size_t)(bs0 + 16 + lr) * rstr + oct * 8;
      f32x4 oac0 = ZERO4, oac1 = ZERO4;
      #pragma unroll
      for (int i = 0; i < 16; ++i) {
        if (i >= n_ent) break;
        _Float16 pw0 = s_p16[i * 132 + lr * 4 + wv];
        _Float16 pw1 = s_p16[i * 132 + (16 + lr) * 4 + wv];
        f16x8 fr0, fr1;
        if (oct < 3) {
          float4 a = *(const float4*)(rpv0 + i * 24);
          float4 b = *(const float4*)(rpv0 + i * 24 + 4);
          fr0[0] = (_Float16)a.x * pw0; fr0[1] = (_Float16)a.y * pw0;
          fr0[2] = (_Float16)a.z * pw0; fr0[3] = (_Float16)a.w * pw0;
          fr0[4] = (_Float16)b.x * pw0; fr0[5] = (_Float16)b.y * pw0;
          fr0[6] = (_Float16)b.z * pw0; fr0[7] = (_Float16)b.w * pw0;
          float4 c = *(const float4*)(rpv1 + i * 24);
          float4 d = *(const float4*)(rpv1 + i * 24 + 4);
          fr1[0] = (_Float16)c.x * pw1; fr1[1] = (_Float16)c.y * pw1;
          fr1[2] = (_Float16)c.z * pw1; fr1[3] = (_Float16)c.w * pw1;
          fr1[4] = (_Float16)d.x * pw1; fr1[5] = (_Float16)d.y * pw1;
          fr1[6] = (_Float16)d.z * pw1; fr1[7] = (_Float16)d.w * pw1;
        } else {
          fr0 = ZERO8F; fr0[0] = pw0;
          fr1 = ZERO8F; fr1[0] = pw1;
        }
        oac0 = MFH(fr0, vbF, oac0);
        oac1 = MFH(fr1, vbF, oac1);
      }
      __syncthreads();   // w16 reads (score) fully done before att16 overwrite
      #pragma unroll
      for (int j = 0; j < 4; ++j) {
        s_att16[(oct * 4 + j) * 68 + wv * 16 + lr]      = (_Float16)oac0[j];
        s_att16[(16 + oct * 4 + j) * 68 + wv * 16 + lr] = (_Float16)oac1[j];
      }
    }
    __syncthreads();

    // --- o-GEMM -> u[:, 64+side*64] (2 row-tiles, shared B) ---
    {
      f16x8 b0 = *(const f16x8*)(woT + (wv * 16 + lr) * 64 + oct * 8);
      f16x8 b1 = *(const f16x8*)(woT + (wv * 16 + lr) * 64 + 32 + oct * 8);
      #pragma unroll
      for (int rt = 0; rt < 2; ++rt) {
        f16x8 a0 = *(const f16x8*)(s_att16 + (rt * 16 + lr) * 68 + oct * 8);
        f16x8 a1 = *(const f16x8*)(s_att16 + (rt * 16 + lr) * 68 + 32 + oct * 8);
        f32x4 oa = ZERO4;
        oa = MFH(a0, b0, oa);
        oa = MFH(a1, b1, oa);
        #pragma unroll
        for (int j = 0; j < 4; ++j)
          s_u16[(rt * 16 + oct * 4 + j) * 196 + 64 + side * 64 + wv * 16 + lr] = (_Float16)oa[j];
      }
    }
    __syncthreads();
  }

  // ---------------- phase 4: GRU (f16 MFMA, 2 row-tiles, shared B) ---------
  {
    const _Float16* ihT = (const _Float16*)((const char*)ws + OFF_GIH);
    const _Float16* hhT = (const _Float16*)((const char*)ws + OFF_GHH);
    const float* gbS = (const float*)((const char*)ws + OFF_GBS);
    const float* gbH = (const float*)((const char*)ws + OFF_GBH);
    f32x4 aX0[2] = {ZERO4, ZERO4}, aX1[2] = {ZERO4, ZERO4};
    f32x4 aX2[2] = {ZERO4, ZERO4}, aH2[2] = {ZERO4, ZERO4};
    #pragma unroll
    for (int st = 0; st < 6; ++st) {
      f16x8 uf0 = *(const f16x8*)(s_u16 + lr * 196 + st * 32 + oct * 8);
      f16x8 uf1 = *(const f16x8*)(s_u16 + (16 + lr) * 196 + st * 32 + oct * 8);
      f16x8 b0 = *(const f16x8*)(ihT + ((wv    ) * 16 + lr) * 192 + st * 32 + oct * 8);
      f16x8 b1 = *(const f16x8*)(ihT + ((wv + 4) * 16 + lr) * 192 + st * 32 + oct * 8);
      f16x8 b2 = *(const f16x8*)(ihT + ((wv + 8) * 16 + lr) * 192 + st * 32 + oct * 8);
      aX0[0] = MFH(uf0, b0, aX0[0]);  aX0[1] = MFH(uf1, b0, aX0[1]);
      aX1[0] = MFH(uf0, b1, aX1[0]);  aX1[1] = MFH(uf1, b1, aX1[1]);
      aX2[0] = MFH(uf0, b2, aX2[0]);  aX2[1] = MFH(uf1, b2, aX2[1]);
    }
    #pragma unroll
    for (int st = 0; st < 2; ++st) {
      f16x8 hf0 = *(const f16x8*)(s_hid16 + lr * 68 + st * 32 + oct * 8);
      f16x8 hf1 = *(const f16x8*)(s_hid16 + (16 + lr) * 68 + st * 32 + oct * 8);
      f16x8 b0 = *(const f16x8*)(hhT + ((wv    ) * 16 + lr) * 64 + st * 32 + oct * 8);
      f16x8 b1 = *(const f16x8*)(hhT + ((wv + 4) * 16 + lr) * 64 + st * 32 + oct * 8);
      f16x8 b2 = *(const f16x8*)(hhT + ((wv + 8) * 16 + lr) * 64 + st * 32 + oct * 8);
      aX0[0] = MFH(hf0, b0, aX0[0]);  aX0[1] = MFH(hf1, b0, aX0[1]);
      aX1[0] = MFH(hf0, b1, aX1[0]);  aX1[1] = MFH(hf1, b1, aX1[1]);
      aH2[0] = MFH(hf0, b2, aH2[0]);  aH2[1] = MFH(hf1, b2, aH2[1]);
    }
    const int c0 = wv * 16 + lr;
    float bb0 = gbS[c0], bb1 = gbS[c0 + 64], bb2 = gbS[c0 + 128], bbh = gbH[c0];
    __syncthreads();   // all s_u16 reads done before z16 overwrites R2
    #pragma unroll
    for (int rt = 0; rt < 2; ++rt) {
      #pragma unroll
      for (int j = 0; j < 4; ++j) {
        int row = rt * 16 + oct * 4 + j;
        float xr = aX0[rt][j] + bb0;
        float xz = aX1[rt][j] + bb1;
        float xn = aX2[rt][j] + bb2;
        float hn = aH2[rt][j] + bbh;
        float r  = __builtin_amdgcn_rcpf(1.f + __builtin_exp2f(-xr * LOG2E));
        float zg = __builtin_amdgcn_rcpf(1.f + __builtin_exp2f(-xz * LOG2E));
        float ta = xn + r * hn;
        float nc = 1.f - 2.f * __builtin_amdgcn_rcpf(1.f + __builtin_exp2f(2.f * LOG2E * ta));
        float hv = (float)s_hid16[row * 68 + c0];
        s_z16[row * 68 + c0] = (_Float16)((1.f - zg) * nc + zg * hv);
      }
    }
  }
  __syncthreads();

  // ---------------- phase 5: fused head GEMM (all 4 waves) -----------------
  {
    const _Float16* bhT = (const _Float16*)((const char*)ws + OFF_BHD);
    const int rt = wv >> 1;
    const int col = (wv & 1) * 16 + lr;
    f16x8 a0 = *(const f16x8*)(s_z16 + (rt * 16 + lr) * 68 + oct * 8);
    f16x8 a1 = *(const f16x8*)(s_z16 + (rt * 16 + lr) * 68 + 32 + oct * 8);
    f16x8 b0 = *(const f16x8*)(bhT + col * 64 + oct * 8);
    f16x8 b1 = *(const f16x8*)(bhT + col * 64 + 32 + oct * 8);
    f32x4 td = ZERO4;
    td = MFH(a0, b0, td);
    td = MFH(a1, b1, td);
    #pragma unroll
    for (int j = 0; j < 4; ++j) {
      int row = rt * 16 + oct * 4 + j;
      if (col < 25)      s_t16[row * 26 + col] = (_Float16)td[j];
      else if (col < 31) s_q[row * 22 + (col - 25)] = td[j] + bm[col - 25];
    }
  }
  __syncthreads();
  // shoot logits: thread (s8, entities sh & sh+8)
  {
    const _Float16* tp = s_t16 + s8 * 26;
    #pragma unroll
    for (int e = 0; e < 2; ++e) {
      int m = sh + e * 8;
      const float* er = enemy_raw + (size_t)(bs0 + s8) * 384 + m * 24;
      float acc2 = (float)tp[24];
      #pragma unroll
      for (int k4 = 0; k4 < 6; ++k4) {
        float4 r4 = *(const float4*)(er + k4 * 4);
        acc2 += r4.x * (float)tp[k4*4]   + r4.y * (float)tp[k4*4+1]
              + r4.z * (float)tp[k4*4+2] + r4.w * (float)tp[k4*4+3];
      }
      s_q[s8 * 22 + 6 + m] = acc2;
    }
  }
  __syncthreads();
  // coalesced output tail
  for (int i = tid; i < 704; i += 256)
    out[(size_t)bs0 * 22 + i] = s_q[i];
  for (int i = tid; i < 2048; i += 256)
    out[(size_t)BN * 22 + (size_t)bs0 * 64 + i] = (float)s_z16[(i >> 6) * 68 + (i & 63)];
}

// ============================================================= launch =======
extern "C" void kernel_launch(void* const* d_in, const int* in_sizes, int n_in,
                              void* d_out, int out_size, void* d_ws, size_t ws_size,
                              hipStream_t stream) {
  (void)n_in; (void)out_size; (void)ws_size;
  const float* own_raw   = (const float*)d_in[0];
  const float* ally_raw  = (const float*)d_in[1];
  const float* enemy_raw = (const float*)d_in[2];
  const float* hidden    = (const float*)d_in[3];
  const float* hyp_W1    = (const float*)d_in[4];
  const float* hyp_b1    = (const float*)d_in[5];
  const float* hyp_W2    = (const float*)d_in[6];
  const float* hyp_b2    = (const float*)d_in[7];
  const float* Wa        = (const float*)d_in[8];
  const float* ba        = (const float*)d_in[9];
  const float* We        = (const float*)d_in[10];
  const float* be        = (const float*)d_in[11];
  const float* aWq       = (const float*)d_in[12];
  const float* aWk       = (const float*)d_in[13];
  const float* aWv       = (const float*)d_in[14];
  const float* aWo       = (const float*)d_in[15];
  const float* eWq       = (const float*)d_in[16];
  const float* eWk       = (const float*)d_in[17];
  const float* eWv       = (const float*)d_in[18];
  const float* eWo       = (const float*)d_in[19];
  const float* gWih      = (const float*)d_in[20];
  const float* gWhh      = (const float*)d_in[21];
  const float* gbih      = (const float*)d_in[22];
  const float* gbhh      = (const float*)d_in[23];
  const float* Wm        = (const float*)d_in[24];
  const float* bm        = (const float*)d_in[25];
  const float* WzK       = (const float*)d_in[26];
  const float* WEK       = (const float*)d_in[27];
  int BN = in_sizes[0] / 40;
  int blocks = BN / TB;

  hipLaunchKernelGGL(prep_kernel, dim3(53), dim3(256), 0, stream,
                     hyp_W1, hyp_b1, hyp_W2, hyp_b2, Wa, ba, We, be,
                     aWq, aWk, aWv, aWo, eWq, eWk, eWv, eWo,
                     gWih, gWhh, gbih, gbhh, WzK, WEK, Wm, d_ws);
  hipLaunchKernelGGL(agent_kernel, dim3(blocks), dim3(256), 0, stream,
                     own_raw, ally_raw, enemy_raw, hidden, bm,
                     d_ws, (float*)d_out, BN);
}

// Round 14
// 146.731 us; speedup vs baseline: 1.5065x; 1.0704x over previous
//
#include <hip/hip_runtime.h>
#include <hip/hip_bf16.h>
#include <math.h>

#define TB 32
#define LOG2E 1.44269504f

typedef float f32x4 __attribute__((ext_vector_type(4)));
typedef _Float16 f16x8 __attribute__((ext_vector_type(8)));
typedef _Float16 f16x4 __attribute__((ext_vector_type(4)));
typedef _Float16 f16x2 __attribute__((ext_vector_type(2)));

// ---------------- ws layout (bytes), all weight mats f16 [col][k] -----------
#define OFF_W1T  344064
#define OFF_WOA  352256   // [64][64] = aWo^T
#define OFF_WOE  360448   // [64][64] = eWo^T
#define OFF_VBA  368640   // [64h][32k] = We@Wv fused (k=24 bias row)
#define OFF_VBE  372736
#define OFF_GA   376832   // [128][64]
#define OFF_GE   393216
#define OFF_GIH  409600
#define OFF_GHH  483328
#define OFF_GBS  507904
#define OFF_GBH  508672
#define OFF_BHD  508928

#define MFH(a, b, c) __builtin_amdgcn_mfma_f32_16x16x32_f16((a), (b), (c), 0, 0, 0)

__device__ inline float dot2(f16x2 a, f16x2 b, float c) {
#if __has_builtin(__builtin_amdgcn_fdot2)
  return __builtin_amdgcn_fdot2(a, b, c, false);
#else
  return c + (float)a[0] * (float)b[0] + (float)a[1] * (float)b[1];
#endif
}
__device__ inline f16x2 pk2(float x, float y) {
  f16x2 r; r[0] = (_Float16)x; r[1] = (_Float16)y; return r;
}

// ============================================================= prep =========
__global__ __launch_bounds__(256)
void prep_kernel(const float* __restrict__ hyp_W1, const float* __restrict__ hyp_b1,
                 const float* __restrict__ hyp_W2, const float* __restrict__ hyp_b2,
                 const float* __restrict__ Wa, const float* __restrict__ ba,
                 const float* __restrict__ We, const float* __restrict__ be,
                 const float* __restrict__ aWq, const float* __restrict__ aWk,
                 const float* __restrict__ aWv, const float* __restrict__ aWo,
                 const float* __restrict__ eWq, const float* __restrict__ eWk,
                 const float* __restrict__ eWv, const float* __restrict__ eWo,
                 const float* __restrict__ gWih, const float* __restrict__ gWhh,
                 const float* __restrict__ gbih, const float* __restrict__ gbhh,
                 const float* __restrict__ WzK, const float* __restrict__ WEK,
                 const float* __restrict__ Wm,
                 void* __restrict__ ws)
{
  const int b = blockIdx.x, t = threadIdx.x;
  if (b < 42) {
    _Float16* o = (_Float16*)ws;
    for (int i = t; i < 4096; i += 256) {
      int h = i >> 6, k = i & 63;
      float v;
      if (b < 40)       v = hyp_W2[(size_t)k * 2628 + b * 64 + h];
      else if (b == 40) v = hyp_W2[(size_t)k * 2628 + 2560 + h];
      else              v = (k < 40) ? hyp_b2[k * 64 + h]
                             : (k == 40 ? hyp_b2[2560 + h] : 0.0f);
      o[b * 4096 + i] = (_Float16)v;
    }
  } else if (b == 42) {
    _Float16* o = (_Float16*)((char*)ws + OFF_W1T);
    for (int i = t; i < 4096; i += 256) {
      int h = i >> 6, k = i & 63;
      float v = (k < 40) ? hyp_W1[k * 64 + h] : (k == 40 ? hyp_b1[h] : 0.0f);
      o[i] = (_Float16)v;
    }
  } else if (b == 43 || b == 44) {
    const float* M = (b == 43) ? aWo : eWo;
    _Float16* o = (_Float16*)((char*)ws + (b == 43 ? OFF_WOA : OFF_WOE));
    for (int i = t; i < 4096; i += 256)
      o[i] = (_Float16)M[(i & 63) * 64 + (i >> 6)];
  } else if (b == 45 || b == 46) {
    const float* Wemb = (b == 45) ? Wa : We;
    const float* bemb = (b == 45) ? ba : be;
    const float* Wv   = (b == 45) ? aWv : eWv;
    _Float16* o = (_Float16*)((char*)ws + (b == 45 ? OFF_VBA : OFF_VBE));
    for (int i = t; i < 2048; i += 256) {
      int h = i >> 5, k = i & 31;
      float v = 0.f;
      if (k < 24)       { for (int d = 0; d < 64; ++d) v += Wemb[k * 64 + d] * Wv[d * 64 + h]; }
      else if (k == 24) { for (int d = 0; d < 64; ++d) v += bemb[d] * Wv[d * 64 + h]; }
      o[i] = (_Float16)v;
    }
  } else if (b == 47 || b == 48) {
    const float* Wemb = (b == 47) ? Wa : We;
    const float* bemb = (b == 47) ? ba : be;
    const float* Wk   = (b == 47) ? aWk : eWk;
    const float* Wq   = (b == 47) ? aWq : eWq;
    _Float16* o = (_Float16*)((char*)ws + (b == 47 ? OFF_GA : OFF_GE));
    __shared__ float sKb[25 * 64];
    for (int i = t; i < 1600; i += 256) {
      int k = i >> 6, c = i & 63;
      float v = 0.f;
      if (k < 24)  { for (int d = 0; d < 64; ++d) v += Wemb[k * 64 + d] * Wk[d * 64 + c]; }
      else         { for (int d = 0; d < 64; ++d) v += bemb[d] * Wk[d * 64 + c]; }
      sKb[i] = v;
    }
    __syncthreads();
    for (int i = t; i < 8192; i += 256) {
      int col = i >> 6, d = i & 63;
      int h = col >> 5, kk = col & 31;
      float v = 0.f;
      if (kk < 25)
        for (int dh = 0; dh < 16; ++dh)
          v += Wq[d * 64 + h * 16 + dh] * sKb[kk * 64 + h * 16 + dh];
      o[i] = (_Float16)(v * 0.25f * LOG2E);
    }
  } else if (b == 49) {
    _Float16* o = (_Float16*)((char*)ws + OFF_GIH);
    for (int i = t; i < 36864; i += 256) {
      int d = i / 192, c = i - d * 192;
      o[c * 192 + d] = (_Float16)gWih[i];
    }
  } else if (b == 50) {
    _Float16* o = (_Float16*)((char*)ws + OFF_GHH);
    for (int i = t; i < 12288; i += 256) {
      int d = i / 192, c = i - d * 192;
      o[c * 64 + d] = (_Float16)gWhh[i];
    }
  } else if (b == 51) {
    float* gbS = (float*)((char*)ws + OFF_GBS);
    float* gbH = (float*)((char*)ws + OFF_GBH);
    if (t < 192) gbS[t] = gbih[t] + (t < 128 ? gbhh[t] : 0.0f);
    if (t < 64)  gbH[t] = gbhh[128 + t];
  } else if (b == 52) { // head B-matrix
    __shared__ float sWsK[24 * 64];
    __shared__ float sbw[64];
    _Float16* o = (_Float16*)((char*)ws + OFF_BHD);
    for (int i = t; i < 1536; i += 256) {
      int j = i >> 6, h = i & 63;
      float v = 0.f;
      for (int c = 0; c < 64; ++c) v += We[j * 64 + c] * WEK[c * 64 + h];
      sWsK[i] = v;
    }
    if (t < 64) {
      float v = 0.f;
      for (int c = 0; c < 64; ++c) v += be[c] * WEK[c * 64 + t];
      sbw[t] = v;
    }
    __syncthreads();
    for (int i = t; i < 2048; i += 256) {
      int col = i >> 6, c = i & 63;
      float v = 0.f;
      if (col < 24)       { for (int d = 0; d < 64; ++d) v += WzK[c * 64 + d] * sWsK[col * 64 + d]; }
      else if (col == 24) { for (int d = 0; d < 64; ++d) v += WzK[c * 64 + d] * sbw[d]; }
      else if (col < 31)  v = Wm[c * 6 + (col - 25)];
      o[i] = (_Float16)v;
    }
  }
}

// score helper: 6 float4 raw + w-row -> 4 head scores (masked), all in regs
#define SCORE_BODY(Q0,Q1,Q2,Q3,Q4,Q5,WP,SCV)                                  \
  {                                                                            \
    unsigned orv =                                                             \
      ((Q0.x!=0.f)|(Q0.y!=0.f)|(Q0.z!=0.f)|(Q0.w!=0.f)|                        \
       (Q1.x!=0.f)|(Q1.y!=0.f)|(Q1.z!=0.f)|(Q1.w!=0.f)|                        \
       (Q2.x!=0.f)|(Q2.y!=0.f)|(Q2.z!=0.f)|(Q2.w!=0.f)|                        \
       (Q3.x!=0.f)|(Q3.y!=0.f)|(Q3.z!=0.f)|(Q3.w!=0.f)|                        \
       (Q4.x!=0.f)|(Q4.y!=0.f)|(Q4.z!=0.f)|(Q4.w!=0.f)|                        \
       (Q5.x!=0.f)|(Q5.y!=0.f)|(Q5.z!=0.f)|(Q5.w!=0.f)) ? 1u : 0u;             \
    f16x2 r0 = pk2(Q0.x,Q0.y), r1 = pk2(Q0.z,Q0.w);                            \
    f16x2 r2 = pk2(Q1.x,Q1.y), r3 = pk2(Q1.z,Q1.w);                            \
    f16x2 r4 = pk2(Q2.x,Q2.y), r5 = pk2(Q2.z,Q2.w);                            \
    f16x2 r6 = pk2(Q3.x,Q3.y), r7 = pk2(Q3.z,Q3.w);                            \
    f16x2 r8 = pk2(Q4.x,Q4.y), r9 = pk2(Q4.z,Q4.w);                            \
    f16x2 r10 = pk2(Q5.x,Q5.y), r11 = pk2(Q5.z,Q5.w);                          \
    _Pragma("unroll")                                                          \
    for (int h = 0; h < 4; ++h) {                                              \
      const _Float16* wq = (WP) + h * 32;                                      \
      float a = (float)wq[24];                                                 \
      a = dot2(r0,  *(const f16x2*)(wq + 0),  a);                              \
      a = dot2(r1,  *(const f16x2*)(wq + 2),  a);                              \
      a = dot2(r2,  *(const f16x2*)(wq + 4),  a);                              \
      a = dot2(r3,  *(const f16x2*)(wq + 6),  a);                              \
      a = dot2(r4,  *(const f16x2*)(wq + 8),  a);                              \
      a = dot2(r5,  *(const f16x2*)(wq + 10), a);                              \
      a = dot2(r6,  *(const f16x2*)(wq + 12), a);                              \
      a = dot2(r7,  *(const f16x2*)(wq + 14), a);                              \
      a = dot2(r8,  *(const f16x2*)(wq + 16), a);                              \
      a = dot2(r9,  *(const f16x2*)(wq + 18), a);                              \
      a = dot2(r10, *(const f16x2*)(wq + 20), a);                              \
      a = dot2(r11, *(const f16x2*)(wq + 22), a);                              \
      SCV[h] = orv ? a : -1.0e9f;                                              \
    }                                                                          \
  }

// ============================================================= main =========
__global__ __launch_bounds__(256, 4)
void agent_kernel(
    const float* __restrict__ own_raw, const float* __restrict__ ally_raw,
    const float* __restrict__ enemy_raw, const float* __restrict__ hidden,
    const float* __restrict__ bm,
    const void* __restrict__ ws,
    float* __restrict__ out, int BN)
{
  // LDS = 12544 (u16) + 25088 (R2 union) = 37632 B -> 4 blocks/CU (grid-bound)
  __shared__ __align__(16) char s_all[37632];
  _Float16* s_u16 = (_Float16*)s_all;              // [32][196]
  char*     sR2   = s_all + 12544;                 // 25088 B union
  // ph0-2 : own16 @0 [32][52]=3328 | ownT @3328 [40][32]=2560 | h116 @5888 [32][68]=4352
  // ph3   : w16_0 @0 [32][130]=8320 | w16_1 @8320 | p16_0 @16640 [16][132]=4224 | p16_1 @20864
  //         att0 = alias w16_0 [32][68] | att1 = alias w16_1
  //         hid16 @16640 [32][68]=4352 (staged in o-GEMM phase; p16 dead)
  // ph4+  : z16 @0 [32][68] | t16 @4352 [32][26] f16 | q @8320 [32][22] f32
  _Float16* s_own16 = (_Float16*)sR2;
  _Float16* s_ownT  = (_Float16*)(sR2 + 3328);
  _Float16* s_h116  = (_Float16*)(sR2 + 5888);
  _Float16* s_w0    = (_Float16*)sR2;
  _Float16* s_w1    = (_Float16*)(sR2 + 8320);
  _Float16* s_pp0   = (_Float16*)(sR2 + 16640);
  _Float16* s_pp1   = (_Float16*)(sR2 + 20864);
  _Float16* s_att0  = (_Float16*)sR2;
  _Float16* s_att1  = (_Float16*)(sR2 + 8320);
  _Float16* s_hid16 = (_Float16*)(sR2 + 16640);
  _Float16* s_z16   = (_Float16*)sR2;
  _Float16* s_t16   = (_Float16*)(sR2 + 4352);
  float*    s_q     = (float*)(sR2 + 8320);

  const int tid = threadIdx.x;
  const int bs0 = blockIdx.x * TB;
  const int l   = tid & 63;
  const int wv  = tid >> 6;
  const int lr  = l & 15;
  const int oct = l >> 4;
  const int s8  = tid >> 3;
  const int sh  = tid & 7;

  const f16x8 ZERO8F = {0,0,0,0,0,0,0,0};
  f16x8 ONE8F = ZERO8F; ONE8F[0] = (_Float16)1.0f;
  const f32x4 ZERO4 = {0.f, 0.f, 0.f, 0.f};

  // ---------------- phase 0: stage own (f16 + f16-T) ----------------
  for (int i = tid; i < 640; i += 256) {
    int ss = i / 20, c = i - ss * 20;
    float2 v = *(const float2*)(own_raw + (size_t)(bs0 + ss) * 40 + c * 2);
    *(f16x2*)(s_own16 + ss * 52 + c * 2) = pk2(v.x, v.y);
  }
  for (int i = tid; i < 1280; i += 256) {
    int f = i >> 5, s2 = i & 31;
    s_ownT[i] = (_Float16)own_raw[(size_t)(bs0 + s2) * 40 + f];
  }
  __syncthreads();

  // ---------------- phase 1: h1 = relu(own @ W1 + b1), 2 row-tiles ---------
  {
    const _Float16* w1t = (const _Float16*)((const char*)ws + OFF_W1T);
    f16x8 b0 = *(const f16x8*)(w1t + (wv * 16 + lr) * 64 + oct * 8);
    f16x8 b1 = *(const f16x8*)(w1t + (wv * 16 + lr) * 64 + 32 + oct * 8);
    #pragma unroll
    for (int rt = 0; rt < 2; ++rt) {
      f16x8 a0 = *(const f16x8*)(s_own16 + (rt * 16 + lr) * 52 + oct * 8);
      f16x8 a1;
      if (oct == 0)      a1 = *(const f16x8*)(s_own16 + (rt * 16 + lr) * 52 + 32);
      else if (oct == 1) a1 = ONE8F;
      else               a1 = ZERO8F;
      f32x4 acc = ZERO4;
      acc = MFH(a0, b0, acc);
      acc = MFH(a1, b1, acc);
      #pragma unroll
      for (int j = 0; j < 4; ++j)
        s_h116[(rt * 16 + oct * 4 + j) * 68 + wv * 16 + lr] = (_Float16)fmaxf(acc[j], 0.f);
    }
  }
  __syncthreads();

  // ---------------- phase 2: own_e, scale-in-acc, 2 row-tiles, shared B ----
  {
    const _Float16* bb = (const _Float16*)ws + (size_t)(wv * 16 + lr) * 64 + oct * 8;
    f16x8 h0f0 = *(const f16x8*)(s_h116 + lr * 68 + oct * 8);
    f16x8 h1f0 = *(const f16x8*)(s_h116 + lr * 68 + 32 + oct * 8);
    f16x8 h0f1 = *(const f16x8*)(s_h116 + (16 + lr) * 68 + oct * 8);
    f16x8 h1f1 = *(const f16x8*)(s_h116 + (16 + lr) * 68 + 32 + oct * 8);
    f32x4 acc0 = ZERO4, acc1 = ZERO4;
    #pragma unroll 4
    for (int f = 0; f < 40; ++f) {
      f16x8 b0 = *(const f16x8*)(bb + (size_t)f * 4096);
      f16x8 b1 = *(const f16x8*)(bb + (size_t)f * 4096 + 32);
      f32x4 y0 = MFH(h0f0, b0, ZERO4); y0 = MFH(h1f0, b1, y0);
      f32x4 y1 = MFH(h0f1, b0, ZERO4); y1 = MFH(h1f1, b1, y1);
      f16x4 ov0 = *(const f16x4*)(s_ownT + f * 32 + oct * 4);
      f16x4 ov1 = *(const f16x4*)(s_ownT + f * 32 + 16 + oct * 4);
      #pragma unroll
      for (int j = 0; j < 4; ++j) {
        acc0[j] += (float)ov0[j] * y0[j];
        acc1[j] += (float)ov1[j] * y1[j];
      }
    }
    f32x4 aD0 = ZERO4, aD1 = ZERO4;
    {
      f16x8 b0 = *(const f16x8*)(bb + (size_t)40 * 4096);
      f16x8 b1 = *(const f16x8*)(bb + (size_t)40 * 4096 + 32);
      aD0 = MFH(h0f0, b0, aD0); aD0 = MFH(h1f0, b1, aD0);
      aD1 = MFH(h0f1, b0, aD1); aD1 = MFH(h1f1, b1, aD1);
    }
    {
      f16x8 b0 = *(const f16x8*)(bb + (size_t)41 * 4096);
      f16x8 b1 = *(const f16x8*)(bb + (size_t)41 * 4096 + 32);
      #pragma unroll
      for (int rt = 0; rt < 2; ++rt) {
        f16x8 a0 = *(const f16x8*)(s_own16 + (rt * 16 + lr) * 52 + oct * 8);
        f16x8 a1;
        if (oct == 0)      a1 = *(const f16x8*)(s_own16 + (rt * 16 + lr) * 52 + 32);
        else if (oct == 1) a1 = ONE8F;
        else               a1 = ZERO8F;
        if (rt) { aD1 = MFH(a0, b0, aD1); aD1 = MFH(a1, b1, aD1); }
        else    { aD0 = MFH(a0, b0, aD0); aD0 = MFH(a1, b1, aD0); }
      }
    }
    #pragma unroll
    for (int j = 0; j < 4; ++j) {
      s_u16[(oct * 4 + j) * 196 + wv * 16 + lr]      = (_Float16)(acc0[j] + aD0[j]);
      s_u16[(16 + oct * 4 + j) * 196 + wv * 16 + lr] = (_Float16)(acc1[j] + aD1[j]);
    }
  }
  __syncthreads();

  // ---------------- phase 3a: w = own_e @ G, BOTH sides --------------------
  {
    f16x8 a00 = *(const f16x8*)(s_u16 + lr * 196 + oct * 8);
    f16x8 a10 = *(const f16x8*)(s_u16 + lr * 196 + 32 + oct * 8);
    f16x8 a01 = *(const f16x8*)(s_u16 + (16 + lr) * 196 + oct * 8);
    f16x8 a11 = *(const f16x8*)(s_u16 + (16 + lr) * 196 + 32 + oct * 8);
    #pragma unroll
    for (int side = 0; side < 2; ++side) {
      const _Float16* gT = (const _Float16*)((const char*)ws + (side ? OFF_GE : OFF_GA));
      _Float16* wDst = side ? s_w1 : s_w0;
      #pragma unroll
      for (int t2 = 0; t2 < 2; ++t2) {
        int col = wv * 32 + t2 * 16 + lr;
        f16x8 b0 = *(const f16x8*)(gT + col * 64 + oct * 8);
        f16x8 b1 = *(const f16x8*)(gT + col * 64 + 32 + oct * 8);
        f32x4 ac0 = ZERO4, ac1 = ZERO4;
        ac0 = MFH(a00, b0, ac0); ac0 = MFH(a10, b1, ac0);
        ac1 = MFH(a01, b0, ac1); ac1 = MFH(a11, b1, ac1);
        #pragma unroll
        for (int j = 0; j < 4; ++j) {
          wDst[(oct * 4 + j) * 130 + col]      = (_Float16)ac0[j];
          wDst[(16 + oct * 4 + j) * 130 + col] = (_Float16)ac1[j];
        }
      }
    }
  }
  __syncthreads();

  // ---------------- phase 3b: score BOTH sides (4 rows/thread) -------------
  {
    #pragma unroll
    for (int side = 0; side < 2; ++side) {
      const int n_ent = side ? 16 : 15;
      const int rstr  = side ? 384 : 360;
      const float* rawg = side ? enemy_raw : ally_raw;
      const _Float16* wp = (side ? s_w1 : s_w0) + s8 * 130;
      _Float16* pp = side ? s_pp1 : s_pp0;

      const int n1 = (sh + 8 < n_ent) ? (sh + 8) : (n_ent - 1);
      const float* rp0 = rawg + (size_t)(bs0 + s8) * rstr + sh * 24;
      const float* rp1 = rawg + (size_t)(bs0 + s8) * rstr + n1 * 24;
      float4 qa0 = *(const float4*)(rp0);      float4 qa1 = *(const float4*)(rp0 + 4);
      float4 qa2 = *(const float4*)(rp0 + 8);  float4 qa3 = *(const float4*)(rp0 + 12);
      float4 qa4 = *(const float4*)(rp0 + 16); float4 qa5 = *(const float4*)(rp0 + 20);
      float4 qb0 = *(const float4*)(rp1);      float4 qb1 = *(const float4*)(rp1 + 4);
      float4 qb2 = *(const float4*)(rp1 + 8);  float4 qb3 = *(const float4*)(rp1 + 12);
      float4 qb4 = *(const float4*)(rp1 + 16); float4 qb5 = *(const float4*)(rp1 + 20);

      f32x4 sc0, sc1;
      SCORE_BODY(qa0, qa1, qa2, qa3, qa4, qa5, wp, sc0);
      SCORE_BODY(qb0, qb1, qb2, qb3, qb4, qb5, wp, sc1);
      if (sh + 8 >= n_ent) {
        #pragma unroll
        for (int h = 0; h < 4; ++h) sc1[h] = -2.0e9f;
      }
      f32x4 m, lsum, p0v, p1v;
      #pragma unroll
      for (int h = 0; h < 4; ++h) m[h] = fmaxf(sc0[h], sc1[h]);
      #pragma unroll
      for (int d = 1; d < 8; d <<= 1) {
        #pragma unroll
        for (int h = 0; h < 4; ++h) m[h] = fmaxf(m[h], __shfl_xor(m[h], d));
      }
      #pragma unroll
      for (int h = 0; h < 4; ++h) {
        p0v[h] = __builtin_exp2f(sc0[h] - m[h]);
        p1v[h] = __builtin_exp2f(sc1[h] - m[h]);
        lsum[h] = p0v[h] + p1v[h];
      }
      #pragma unroll
      for (int d = 1; d < 8; d <<= 1) {
        #pragma unroll
        for (int h = 0; h < 4; ++h) lsum[h] += __shfl_xor(lsum[h], d);
      }
      f32x4 rl;
      #pragma unroll
      for (int h = 0; h < 4; ++h) rl[h] = __builtin_amdgcn_rcpf(lsum[h]);
      {
        f16x4 pk;
        #pragma unroll
        for (int h = 0; h < 4; ++h) pk[h] = (_Float16)(p0v[h] * rl[h]);
        *(f16x4*)(pp + sh * 132 + s8 * 4) = pk;
      }
      if (sh + 8 < n_ent) {
        f16x4 pk;
        #pragma unroll
        for (int h = 0; h < 4; ++h) pk[h] = (_Float16)(p1v[h] * rl[h]);
        *(f16x4*)(pp + (sh + 8) * 132 + s8 * 4) = pk;
      }
    }
  }
  __syncthreads();

  // ---------------- phase 3c: PV BOTH sides (raw from global, L2-hot) ------
  {
    #pragma unroll
    for (int side = 0; side < 2; ++side) {
      const int n_ent = side ? 16 : 15;
      const int rstr  = side ? 384 : 360;
      const float* rawg = side ? enemy_raw : ally_raw;
      const _Float16* vbT = (const _Float16*)((const char*)ws + (side ? OFF_VBE : OFF_VBA));
      const _Float16* pp = side ? s_pp1 : s_pp0;
      _Float16* attD = side ? s_att1 : s_att0;

      f16x8 vbF = *(const f16x8*)(vbT + (wv * 16 + lr) * 32 + oct * 8);
      const float* rpv0 = rawg + (size_t)(bs0 + lr) * rstr + oct * 8;
      const float* rpv1 = rawg + (size_t)(bs0 + 16 + lr) * rstr + oct * 8;
      f32x4 oac0 = ZERO4, oac1 = ZERO4;
      #pragma unroll
      for (int i = 0; i < 16; ++i) {
        if (i >= n_ent) break;
        _Float16 pw0 = pp[i * 132 + lr * 4 + wv];
        _Float16 pw1 = pp[i * 132 + (16 + lr) * 4 + wv];
        f16x8 fr0, fr1;
        if (oct < 3) {
          float4 a = *(const float4*)(rpv0 + i * 24);
          float4 b = *(const float4*)(rpv0 + i * 24 + 4);
          fr0[0] = (_Float16)a.x * pw0; fr0[1] = (_Float16)a.y * pw0;
          fr0[2] = (_Float16)a.z * pw0; fr0[3] = (_Float16)a.w * pw0;
          fr0[4] = (_Float16)b.x * pw0; fr0[5] = (_Float16)b.y * pw0;
          fr0[6] = (_Float16)b.z * pw0; fr0[7] = (_Float16)b.w * pw0;
          float4 c = *(const float4*)(rpv1 + i * 24);
          float4 d = *(const float4*)(rpv1 + i * 24 + 4);
          fr1[0] = (_Float16)c.x * pw1; fr1[1] = (_Float16)c.y * pw1;
          fr1[2] = (_Float16)c.z * pw1; fr1[3] = (_Float16)c.w * pw1;
          fr1[4] = (_Float16)d.x * pw1; fr1[5] = (_Float16)d.y * pw1;
          fr1[6] = (_Float16)d.z * pw1; fr1[7] = (_Float16)d.w * pw1;
        } else {
          fr0 = ZERO8F; fr0[0] = pw0;
          fr1 = ZERO8F; fr1[0] = pw1;
        }
        oac0 = MFH(fr0, vbF, oac0);
        oac1 = MFH(fr1, vbF, oac1);
      }
      if (side == 0) __syncthreads();   // w16/p16 reads of side0 done; att0 safe
      #pragma unroll
      for (int j = 0; j < 4; ++j) {
        attD[(oct * 4 + j) * 68 + wv * 16 + lr]      = (_Float16)oac0[j];
        attD[(16 + oct * 4 + j) * 68 + wv * 16 + lr] = (_Float16)oac1[j];
      }
    }
  }
  __syncthreads();

  // ---------------- phase 3d: o-GEMM BOTH sides + stage hidden -------------
  {
    #pragma unroll
    for (int side = 0; side < 2; ++side) {
      const _Float16* woT = (const _Float16*)((const char*)ws + (side ? OFF_WOE : OFF_WOA));
      const _Float16* attS = side ? s_att1 : s_att0;
      f16x8 b0 = *(const f16x8*)(woT + (wv * 16 + lr) * 64 + oct * 8);
      f16x8 b1 = *(const f16x8*)(woT + (wv * 16 + lr) * 64 + 32 + oct * 8);
      #pragma unroll
      for (int rt = 0; rt < 2; ++rt) {
        f16x8 a0 = *(const f16x8*)(attS + (rt * 16 + lr) * 68 + oct * 8);
        f16x8 a1 = *(const f16x8*)(attS + (rt * 16 + lr) * 68 + 32 + oct * 8);
        f32x4 oa = ZERO4;
        oa = MFH(a0, b0, oa);
        oa = MFH(a1, b1, oa);
        #pragma unroll
        for (int j = 0; j < 4; ++j)
          s_u16[(rt * 16 + oct * 4 + j) * 196 + 64 + side * 64 + wv * 16 + lr] = (_Float16)oa[j];
      }
    }
    for (int i = tid; i < 1024; i += 256) {   // hid16 into dead p16 region
      int ss = i >> 5, c = i & 31;
      float2 v = *(const float2*)(hidden + (size_t)(bs0 + ss) * 64 + c * 2);
      *(f16x2*)(s_hid16 + ss * 68 + c * 2) = pk2(v.x, v.y);
    }
  }
  __syncthreads();

  // ---------------- phase 4: GRU (f16 MFMA, 2 row-tiles, shared B) ---------
  {
    const _Float16* ihT = (const _Float16*)((const char*)ws + OFF_GIH);
    const _Float16* hhT = (const _Float16*)((const char*)ws + OFF_GHH);
    const float* gbS = (const float*)((const char*)ws + OFF_GBS);
    const float* gbH = (const float*)((const char*)ws + OFF_GBH);
    f32x4 aX0[2] = {ZERO4, ZERO4}, aX1[2] = {ZERO4, ZERO4};
    f32x4 aX2[2] = {ZERO4, ZERO4}, aH2[2] = {ZERO4, ZERO4};
    #pragma unroll
    for (int st = 0; st < 6; ++st) {
      f16x8 uf0 = *(const f16x8*)(s_u16 + lr * 196 + st * 32 + oct * 8);
      f16x8 uf1 = *(const f16x8*)(s_u16 + (16 + lr) * 196 + st * 32 + oct * 8);
      f16x8 b0 = *(const f16x8*)(ihT + ((wv    ) * 16 + lr) * 192 + st * 32 + oct * 8);
      f16x8 b1 = *(const f16x8*)(ihT + ((wv + 4) * 16 + lr) * 192 + st * 32 + oct * 8);
      f16x8 b2 = *(const f16x8*)(ihT + ((wv + 8) * 16 + lr) * 192 + st * 32 + oct * 8);
      aX0[0] = MFH(uf0, b0, aX0[0]);  aX0[1] = MFH(uf1, b0, aX0[1]);
      aX1[0] = MFH(uf0, b1, aX1[0]);  aX1[1] = MFH(uf1, b1, aX1[1]);
      aX2[0] = MFH(uf0, b2, aX2[0]);  aX2[1] = MFH(uf1, b2, aX2[1]);
    }
    #pragma unroll
    for (int st = 0; st < 2; ++st) {
      f16x8 hf0 = *(const f16x8*)(s_hid16 + lr * 68 + st * 32 + oct * 8);
      f16x8 hf1 = *(const f16x8*)(s_hid16 + (16 + lr) * 68 + st * 32 + oct * 8);
      f16x8 b0 = *(const f16x8*)(hhT + ((wv    ) * 16 + lr) * 64 + st * 32 + oct * 8);
      f16x8 b1 = *(const f16x8*)(hhT + ((wv + 4) * 16 + lr) * 64 + st * 32 + oct * 8);
      f16x8 b2 = *(const f16x8*)(hhT + ((wv + 8) * 16 + lr) * 64 + st * 32 + oct * 8);
      aX0[0] = MFH(hf0, b0, aX0[0]);  aX0[1] = MFH(hf1, b0, aX0[1]);
      aX1[0] = MFH(hf0, b1, aX1[0]);  aX1[1] = MFH(hf1, b1, aX1[1]);
      aH2[0] = MFH(hf0, b2, aH2[0]);  aH2[1] = MFH(hf1, b2, aH2[1]);
    }
    const int c0 = wv * 16 + lr;
    float bb0 = gbS[c0], bb1 = gbS[c0 + 64], bb2 = gbS[c0 + 128], bbh = gbH[c0];
    #pragma unroll
    for (int rt = 0; rt < 2; ++rt) {
      #pragma unroll
      for (int j = 0; j < 4; ++j) {
        int row = rt * 16 + oct * 4 + j;
        float xr = aX0[rt][j] + bb0;
        float xz = aX1[rt][j] + bb1;
        float xn = aX2[rt][j] + bb2;
        float hn = aH2[rt][j] + bbh;
        float r  = __builtin_amdgcn_rcpf(1.f + __builtin_exp2f(-xr * LOG2E));
        float zg = __builtin_amdgcn_rcpf(1.f + __builtin_exp2f(-xz * LOG2E));
        float ta = xn + r * hn;
        float nc = 1.f - 2.f * __builtin_amdgcn_rcpf(1.f + __builtin_exp2f(2.f * LOG2E * ta));
        float hv = (float)s_hid16[row * 68 + c0];
        s_z16[row * 68 + c0] = (_Float16)((1.f - zg) * nc + zg * hv);
      }
    }
  }
  __syncthreads();

  // ---------------- phase 5: fused head GEMM (all 4 waves) -----------------
  {
    const _Float16* bhT = (const _Float16*)((const char*)ws + OFF_BHD);
    const int rt = wv >> 1;
    const int col = (wv & 1) * 16 + lr;
    f16x8 a0 = *(const f16x8*)(s_z16 + (rt * 16 + lr) * 68 + oct * 8);
    f16x8 a1 = *(const f16x8*)(s_z16 + (rt * 16 + lr) * 68 + 32 + oct * 8);
    f16x8 b0 = *(const f16x8*)(bhT + col * 64 + oct * 8);
    f16x8 b1 = *(const f16x8*)(bhT + col * 64 + 32 + oct * 8);
    f32x4 td = ZERO4;
    td = MFH(a0, b0, td);
    td = MFH(a1, b1, td);
    #pragma unroll
    for (int j = 0; j < 4; ++j) {
      int row = rt * 16 + oct * 4 + j;
      if (col < 25)      s_t16[row * 26 + col] = (_Float16)td[j];
      else if (col < 31) s_q[row * 22 + (col - 25)] = td[j] + bm[col - 25];
    }
  }
  __syncthreads();
  // shoot logits: thread (s8, entities sh & sh+8)
  {
    const _Float16* tp = s_t16 + s8 * 26;
    #pragma unroll
    for (int e = 0; e < 2; ++e) {
      int m = sh + e * 8;
      const float* er = enemy_raw + (size_t)(bs0 + s8) * 384 + m * 24;
      float acc2 = (float)tp[24];
      #pragma unroll
      for (int k4 = 0; k4 < 6; ++k4) {
        float4 r4 = *(const float4*)(er + k4 * 4);
        acc2 += r4.x * (float)tp[k4*4]   + r4.y * (float)tp[k4*4+1]
              + r4.z * (float)tp[k4*4+2] + r4.w * (float)tp[k4*4+3];
      }
      s_q[s8 * 22 + 6 + m] = acc2;
    }
  }
  __syncthreads();
  // coalesced output tail
  for (int i = tid; i < 704; i += 256)
    out[(size_t)bs0 * 22 + i] = s_q[i];
  for (int i = tid; i < 2048; i += 256)
    out[(size_t)BN * 22 + (size_t)bs0 * 64 + i] = (float)s_z16[(i >> 6) * 68 + (i & 63)];
}

// ============================================================= launch =======
extern "C" void kernel_launch(void* const* d_in, const int* in_sizes, int n_in,
                              void* d_out, int out_size, void* d_ws, size_t ws_size,
                              hipStream_t stream) {
  (void)n_in; (void)out_size; (void)ws_size;
  const float* own_raw   = (const float*)d_in[0];
  const float* ally_raw  = (const float*)d_in[1];
  const float* enemy_raw = (const float*)d_in[2];
  const float* hidden    = (const float*)d_in[3];
  const float* hyp_W1    = (const float*)d_in[4];
  const float* hyp_b1    = (const float*)d_in[5];
  const float* hyp_W2    = (const float*)d_in[6];
  const float* hyp_b2    = (const float*)d_in[7];
  const float* Wa        = (const float*)d_in[8];
  const float* ba        = (const float*)d_in[9];
  const float* We        = (const float*)d_in[10];
  const float* be        = (const float*)d_in[11];
  const float* aWq       = (const float*)d_in[12];
  const float* aWk       = (const float*)d_in[13];
  const float* aWv       = (const float*)d_in[14];
  const float* aWo       = (const float*)d_in[15];
  const float* eWq       = (const float*)d_in[16];
  const float* eWk       = (const float*)d_in[17];
  const float* eWv       = (const float*)d_in[18];
  const float* eWo       = (const float*)d_in[19];
  const float* gWih      = (const float*)d_in[20];
  const float* gWhh      = (const float*)d_in[21];
  const float* gbih      = (const float*)d_in[22];
  const float* gbhh      = (const float*)d_in[23];
  const float* Wm        = (const float*)d_in[24];
  const float* bm        = (const float*)d_in[25];
  const float* WzK       = (const float*)d_in[26];
  const float* WEK       = (const float*)d_in[27];
  int BN = in_sizes[0] / 40;
  int blocks = BN / TB;

  hipLaunchKernelGGL(prep_kernel, dim3(53), dim3(256), 0, stream,
                     hyp_W1, hyp_b1, hyp_W2, hyp_b2, Wa, ba, We, be,
                     aWq, aWk, aWv, aWo, eWq, eWk, eWv, eWo,
                     gWih, gWhh, gbih, gbhh, WzK, WEK, Wm, d_ws);
  hipLaunchKernelGGL(agent_kernel, dim3(blocks), dim3(256), 0, stream,
                     own_raw, ally_raw, enemy_raw, hidden, bm,
                     d_ws, (float*)d_out, BN);
}